// Round 2
// baseline (4546.156 us; speedup 1.0000x reference)
//
#include <hip/hip_runtime.h>
#include <math.h>

#define D_MODEL 512
#define N_LAYERS 4
#define LATENT 1024
#define D_INNER 1024
#define D_STATE 16
#define DT_RANK 32
#define KCONV 4
#define BATCH 4
#define SEQ 1024
#define NTOK (BATCH * SEQ) /* 4096 */

// ---------------------------------------------------------------------------
// Tiled fp32 GEMM: C[M,N] = act(A[M,K] @ B[K,N] (+bias) (+C))
// flags: 1 = add bias[n], 2 = accumulate into existing C, 4 = softplus
// BM=BN=64, BK=16, 256 threads, 4x4 microtile per thread.
// ---------------------------------------------------------------------------
__global__ __launch_bounds__(256) void gemm_kernel(
    const float* __restrict__ A, int lda,
    const float* __restrict__ B, int ldb,
    float* __restrict__ C, int ldc,
    const float* __restrict__ bias,
    int M, int N, int K, int flags)
{
    const int BM = 64, BN = 64, BK = 16;
    __shared__ float As[16][68];
    __shared__ float Bs[16][68];

    const int tid = threadIdx.x;
    const int tx = tid & 15;
    const int ty = tid >> 4;
    const int m0 = blockIdx.y * BM;
    const int n0 = blockIdx.x * BN;

    float acc[4][4] = {};

    for (int k0 = 0; k0 < K; k0 += BK) {
        #pragma unroll
        for (int i = 0; i < (BM * BK) / 256; i++) {
            int idx = tid + i * 256;
            int r = idx >> 4;
            int c = idx & 15;
            As[c][r] = A[(size_t)(m0 + r) * lda + k0 + c];
        }
        #pragma unroll
        for (int i = 0; i < (BK * BN) / 256; i++) {
            int idx = tid + i * 256;
            int r = idx >> 6;
            int c = idx & 63;
            Bs[r][c] = B[(size_t)(k0 + r) * ldb + n0 + c];
        }
        __syncthreads();

        #pragma unroll
        for (int kk = 0; kk < BK; kk++) {
            float a[4], b[4];
            #pragma unroll
            for (int i = 0; i < 4; i++) a[i] = As[kk][ty * 4 + i];
            #pragma unroll
            for (int j = 0; j < 4; j++) b[j] = Bs[kk][tx * 4 + j];
            #pragma unroll
            for (int i = 0; i < 4; i++)
                #pragma unroll
                for (int j = 0; j < 4; j++)
                    acc[i][j] = fmaf(a[i], b[j], acc[i][j]);
        }
        __syncthreads();
    }

    #pragma unroll
    for (int i = 0; i < 4; i++) {
        int m = m0 + ty * 4 + i;
        #pragma unroll
        for (int j = 0; j < 4; j++) {
            int n = n0 + tx * 4 + j;
            float v = acc[i][j];
            if (flags & 1) v += bias[n];
            if (flags & 2) v += C[(size_t)m * ldc + n];
            if (flags & 4) v = (v > 20.f) ? v : log1pf(expf(v));
            C[(size_t)m * ldc + n] = v;
        }
    }
}

// ---------------------------------------------------------------------------
// RMSNorm over rows of D_MODEL=512. One block (256 thr) per row.
// ---------------------------------------------------------------------------
__global__ __launch_bounds__(256) void rmsnorm_kernel(
    const float* __restrict__ x, const float* __restrict__ w,
    float* __restrict__ y)
{
    const int row = blockIdx.x;
    const float* xr = x + (size_t)row * D_MODEL;
    float* yr = y + (size_t)row * D_MODEL;
    const int tid = threadIdx.x;

    float v0 = xr[tid], v1 = xr[tid + 256];
    float ss = v0 * v0 + v1 * v1;
    #pragma unroll
    for (int off = 32; off > 0; off >>= 1) ss += __shfl_down(ss, off);

    __shared__ float wsum[4];
    __shared__ float scale_s;
    int wid = tid >> 6, lane = tid & 63;
    if (lane == 0) wsum[wid] = ss;
    __syncthreads();
    if (tid == 0) {
        float tot = wsum[0] + wsum[1] + wsum[2] + wsum[3];
        scale_s = 1.0f / sqrtf(tot / (float)D_MODEL + 1e-5f);
    }
    __syncthreads();
    float sc = scale_s;
    yr[tid] = v0 * sc * w[tid];
    yr[tid + 256] = v1 * sc * w[tid + 256];
}

// ---------------------------------------------------------------------------
// Causal depthwise conv (K=4) + bias + silu.
// ---------------------------------------------------------------------------
__global__ __launch_bounds__(256) void conv_silu_kernel(
    const float* __restrict__ xz, const float* __restrict__ w,
    const float* __restrict__ bconv, float* __restrict__ out)
{
    const int idx = blockIdx.x * 256 + threadIdx.x;
    const int d = idx & (D_INNER - 1);
    const int t = (idx >> 10) & (SEQ - 1);
    const int b = idx >> 20;
    const float* base = xz + (size_t)b * SEQ * 2 * D_INNER + d;

    float s = 0.f;
    #pragma unroll
    for (int k = 0; k < KCONV; k++) {
        int tt = t - (KCONV - 1) + k;
        if (tt >= 0) s = fmaf(base[(size_t)tt * (2 * D_INNER)], w[d * KCONV + k], s);
    }
    s += bconv[d];
    out[idx] = s / (1.f + expf(-s));
}

// ---------------------------------------------------------------------------
// Selective scan, lane-per-state version, gate fused.
// 16 lanes per channel (one per state n); __shfl_xor(width=16) reduces y.
// Grid: BATCH * D_INNER/16 = 256 blocks of 256 threads (16 channels/block).
// Critical carried dependency: ONE fma per timestep (h = dA*h + dtu*B).
// u buffer overwritten in place with y*silu(z).
// ---------------------------------------------------------------------------
__global__ __launch_bounds__(256) void scan_kernel(
    const float* __restrict__ dtbuf,  // (B,S,D_INNER)
    const float* __restrict__ dbl,    // (B,S,64) cols 32..47=B, 48..63=C
    const float* __restrict__ xz,     // (B,S,2*D_INNER): z = cols D_INNER..
    const float* __restrict__ A_log,  // (D_INNER,16) layer slice
    const float* __restrict__ Dp,     // (D_INNER) layer slice
    float* __restrict__ u)            // (B,S,D_INNER), in: u, out: y*silu(z)
{
    const int tid = threadIdx.x;
    const int g = tid >> 4;          // channel group within block, 0..15
    const int n = tid & 15;          // state index
    const int b = blockIdx.x >> 6;   // batch
    const int d = ((blockIdx.x & 63) << 4) + g;

    const float Aval = -expf(A_log[d * D_STATE + n]);
    const float Dv = Dp[d];

    const float* dtp = dtbuf + (size_t)b * SEQ * D_INNER + d;
    float* up = u + (size_t)b * SEQ * D_INNER + d;
    const float* zp = xz + (size_t)b * SEQ * (2 * D_INNER) + D_INNER + d;
    const float* bcp = dbl + (size_t)b * SEQ * 64 + 32 + n;

    float h = 0.f;

    #pragma unroll 4
    for (int t = 0; t < SEQ; t++) {
        float dtv = dtp[(size_t)t * D_INNER];
        float uv = up[(size_t)t * D_INNER];
        float zv = zp[(size_t)t * (2 * D_INNER)];
        float Bv = bcp[(size_t)t * 64];
        float Cv = bcp[(size_t)t * 64 + 16];

        float dA = __expf(dtv * Aval);
        h = fmaf(dA, h, dtv * uv * Bv);   // the only carried dependency
        float yp = h * Cv;
        yp += __shfl_xor(yp, 1, 16);
        yp += __shfl_xor(yp, 2, 16);
        yp += __shfl_xor(yp, 4, 16);
        yp += __shfl_xor(yp, 8, 16);
        if (n == 0) {
            float res = fmaf(uv, Dv, yp);
            res *= zv / (1.f + expf(-zv));   // fused gate: *silu(z)
            up[(size_t)t * D_INNER] = res;
        }
    }
}

// ---------------------------------------------------------------------------
// Grouped softmax over last-dim groups of 32 (N_CAT).
// ---------------------------------------------------------------------------
__global__ __launch_bounds__(256) void softmax_kernel(
    const float* __restrict__ in, float* __restrict__ out)
{
    const int idx = blockIdx.x * 256 + threadIdx.x;
    float v = in[idx];
    float m = v;
    #pragma unroll
    for (int off = 16; off > 0; off >>= 1) m = fmaxf(m, __shfl_xor(m, off, 32));
    float e = expf(v - m);
    float s = e;
    #pragma unroll
    for (int off = 16; off > 0; off >>= 1) s += __shfl_xor(s, off, 32);
    out[idx] = e / s;
}

// ---------------------------------------------------------------------------
extern "C" void kernel_launch(void* const* d_in, const int* in_sizes, int n_in,
                              void* d_out, int out_size, void* d_ws, size_t ws_size,
                              hipStream_t stream)
{
    const float* x       = (const float*)d_in[0];
    const float* lin1_w  = (const float*)d_in[1];
    const float* lin1_b  = (const float*)d_in[2];
    const float* norm_w  = (const float*)d_in[3];
    const float* in_w    = (const float*)d_in[4];
    const float* conv_w  = (const float*)d_in[5];
    const float* conv_b  = (const float*)d_in[6];
    const float* xproj_w = (const float*)d_in[7];
    const float* dt_w    = (const float*)d_in[8];
    const float* dt_b    = (const float*)d_in[9];
    const float* A_log   = (const float*)d_in[10];
    const float* Dp      = (const float*)d_in[11];
    const float* out_w   = (const float*)d_in[12];
    const float* lin2_w  = (const float*)d_in[13];
    const float* lin2_b  = (const float*)d_in[14];
    float* outp = (float*)d_out;

    float* ws = (float*)d_ws;
    const size_t SZ_H  = (size_t)NTOK * D_MODEL;
    const size_t SZ_XZ = (size_t)NTOK * 2 * D_INNER;
    const size_t SZ_XC = (size_t)NTOK * D_INNER;
    const size_t SZ_DBL = (size_t)NTOK * 64;

    float* h    = ws;
    float* hn   = h + SZ_H;
    float* xz   = hn + SZ_H;
    float* xc   = xz + SZ_XZ;
    float* dbl  = xc + SZ_XC;
    float* dt   = dbl + SZ_DBL;
    (void)ws_size; (void)in_sizes; (void)n_in; (void)out_size;

    dim3 blk(256);

    // lin1: h = x @ lin1_w + lin1_b
    gemm_kernel<<<dim3(D_MODEL / 64, NTOK / 64), blk, 0, stream>>>(
        x, LATENT, lin1_w, D_MODEL, h, D_MODEL, lin1_b,
        NTOK, D_MODEL, LATENT, 1);

    for (int l = 0; l < N_LAYERS; l++) {
        const float* nw  = norm_w + (size_t)l * D_MODEL;
        const float* iw  = in_w + (size_t)l * D_MODEL * 2 * D_INNER;
        const float* cw  = conv_w + (size_t)l * D_INNER * KCONV;
        const float* cb  = conv_b + (size_t)l * D_INNER;
        const float* xw  = xproj_w + (size_t)l * D_INNER * (DT_RANK + 2 * D_STATE);
        const float* dw  = dt_w + (size_t)l * DT_RANK * D_INNER;
        const float* db  = dt_b + (size_t)l * D_INNER;
        const float* al  = A_log + (size_t)l * D_INNER * D_STATE;
        const float* dp  = Dp + (size_t)l * D_INNER;
        const float* ow  = out_w + (size_t)l * D_INNER * D_MODEL;

        rmsnorm_kernel<<<dim3(NTOK), blk, 0, stream>>>(h, nw, hn);

        // xz = hn @ in_w[l]
        gemm_kernel<<<dim3((2 * D_INNER) / 64, NTOK / 64), blk, 0, stream>>>(
            hn, D_MODEL, iw, 2 * D_INNER, xz, 2 * D_INNER, nullptr,
            NTOK, 2 * D_INNER, D_MODEL, 0);

        // xc = silu(conv(xz[:, :D_INNER]) + conv_b)
        conv_silu_kernel<<<dim3((NTOK * D_INNER) / 256), blk, 0, stream>>>(
            xz, cw, cb, xc);

        // dbl = xc @ xproj_w[l]
        gemm_kernel<<<dim3(64 / 64, NTOK / 64), blk, 0, stream>>>(
            xc, D_INNER, xw, 64, dbl, 64, nullptr,
            NTOK, 64, D_INNER, 0);

        // dt = softplus(dbl[:, :32] @ dt_w[l] + dt_b[l])
        gemm_kernel<<<dim3(D_INNER / 64, NTOK / 64), blk, 0, stream>>>(
            dbl, 64, dw, D_INNER, dt, D_INNER, db,
            NTOK, D_INNER, DT_RANK, 1 | 4);

        // selective scan + fused gate: xc -> y*silu(z) in place
        scan_kernel<<<dim3(BATCH * (D_INNER / 16)), blk, 0, stream>>>(
            dt, dbl, xz, al, dp, xc);

        // h += y @ out_w[l]
        gemm_kernel<<<dim3(D_MODEL / 64, NTOK / 64), blk, 0, stream>>>(
            xc, D_INNER, ow, D_MODEL, h, D_MODEL, nullptr,
            NTOK, D_MODEL, D_INNER, 2);
    }

    // logits (reuse xz) = h @ lin2_w + lin2_b
    gemm_kernel<<<dim3(LATENT / 64, NTOK / 64), blk, 0, stream>>>(
        h, D_MODEL, lin2_w, LATENT, xz, LATENT, lin2_b,
        NTOK, LATENT, D_MODEL, 1);

    softmax_kernel<<<dim3((NTOK * LATENT) / 256), blk, 0, stream>>>(xz, outp);
}

// Round 3
// 1663.099 us; speedup vs baseline: 2.7335x; 2.7335x over previous
//
#include <hip/hip_runtime.h>
#include <math.h>

#define D_MODEL 512
#define N_LAYERS 4
#define LATENT 1024
#define D_INNER 1024
#define D_STATE 16
#define DT_RANK 32
#define KCONV 4
#define BATCH 4
#define SEQ 1024
#define NTOK (BATCH * SEQ) /* 4096 */
#define PCH 32   /* chunks per sequence */
#define CLEN 32  /* SEQ / PCH */

// ---------------------------------------------------------------------------
// Tiled fp32 GEMM: C[M,N] = act(A[M,K] @ B[K,N] (+bias) (+C))
// flags: 1 = add bias[n], 2 = accumulate into existing C, 4 = softplus
// ---------------------------------------------------------------------------
__global__ __launch_bounds__(256) void gemm_kernel(
    const float* __restrict__ A, int lda,
    const float* __restrict__ B, int ldb,
    float* __restrict__ C, int ldc,
    const float* __restrict__ bias,
    int M, int N, int K, int flags)
{
    const int BM = 64, BN = 64, BK = 16;
    __shared__ float As[16][68];
    __shared__ float Bs[16][68];

    const int tid = threadIdx.x;
    const int tx = tid & 15;
    const int ty = tid >> 4;
    const int m0 = blockIdx.y * BM;
    const int n0 = blockIdx.x * BN;

    float acc[4][4] = {};

    for (int k0 = 0; k0 < K; k0 += BK) {
        #pragma unroll
        for (int i = 0; i < (BM * BK) / 256; i++) {
            int idx = tid + i * 256;
            int r = idx >> 4;
            int c = idx & 15;
            As[c][r] = A[(size_t)(m0 + r) * lda + k0 + c];
        }
        #pragma unroll
        for (int i = 0; i < (BK * BN) / 256; i++) {
            int idx = tid + i * 256;
            int r = idx >> 6;
            int c = idx & 63;
            Bs[r][c] = B[(size_t)(k0 + r) * ldb + n0 + c];
        }
        __syncthreads();

        #pragma unroll
        for (int kk = 0; kk < BK; kk++) {
            float a[4], b[4];
            #pragma unroll
            for (int i = 0; i < 4; i++) a[i] = As[kk][ty * 4 + i];
            #pragma unroll
            for (int j = 0; j < 4; j++) b[j] = Bs[kk][tx * 4 + j];
            #pragma unroll
            for (int i = 0; i < 4; i++)
                #pragma unroll
                for (int j = 0; j < 4; j++)
                    acc[i][j] = fmaf(a[i], b[j], acc[i][j]);
        }
        __syncthreads();
    }

    #pragma unroll
    for (int i = 0; i < 4; i++) {
        int m = m0 + ty * 4 + i;
        #pragma unroll
        for (int j = 0; j < 4; j++) {
            int n = n0 + tx * 4 + j;
            float v = acc[i][j];
            if (flags & 1) v += bias[n];
            if (flags & 2) v += C[(size_t)m * ldc + n];
            if (flags & 4) v = (v > 20.f) ? v : log1pf(expf(v));
            C[(size_t)m * ldc + n] = v;
        }
    }
}

// ---------------------------------------------------------------------------
// RMSNorm over rows of D_MODEL=512. One block (256 thr) per row.
// ---------------------------------------------------------------------------
__global__ __launch_bounds__(256) void rmsnorm_kernel(
    const float* __restrict__ x, const float* __restrict__ w,
    float* __restrict__ y)
{
    const int row = blockIdx.x;
    const float* xr = x + (size_t)row * D_MODEL;
    float* yr = y + (size_t)row * D_MODEL;
    const int tid = threadIdx.x;

    float v0 = xr[tid], v1 = xr[tid + 256];
    float ss = v0 * v0 + v1 * v1;
    #pragma unroll
    for (int off = 32; off > 0; off >>= 1) ss += __shfl_down(ss, off);

    __shared__ float wsum[4];
    __shared__ float scale_s;
    int wid = tid >> 6, lane = tid & 63;
    if (lane == 0) wsum[wid] = ss;
    __syncthreads();
    if (tid == 0) {
        float tot = wsum[0] + wsum[1] + wsum[2] + wsum[3];
        scale_s = 1.0f / sqrtf(tot / (float)D_MODEL + 1e-5f);
    }
    __syncthreads();
    float sc = scale_s;
    yr[tid] = v0 * sc * w[tid];
    yr[tid + 256] = v1 * sc * w[tid + 256];
}

// ---------------------------------------------------------------------------
// Causal depthwise conv (K=4) + bias + silu.
// ---------------------------------------------------------------------------
__global__ __launch_bounds__(256) void conv_silu_kernel(
    const float* __restrict__ xz, const float* __restrict__ w,
    const float* __restrict__ bconv, float* __restrict__ out)
{
    const int idx = blockIdx.x * 256 + threadIdx.x;
    const int d = idx & (D_INNER - 1);
    const int t = (idx >> 10) & (SEQ - 1);
    const int b = idx >> 20;
    const float* base = xz + (size_t)b * SEQ * 2 * D_INNER + d;

    float s = 0.f;
    #pragma unroll
    for (int k = 0; k < KCONV; k++) {
        int tt = t - (KCONV - 1) + k;
        if (tt >= 0) s = fmaf(base[(size_t)tt * (2 * D_INNER)], w[d * KCONV + k], s);
    }
    s += bconv[d];
    out[idx] = s / (1.f + expf(-s));
}

// ---------------------------------------------------------------------------
// Chunked parallel selective scan, 3 passes. Chunk length CLEN=32.
// Pass 1: per (b, chunk, d) thread runs local scan with h0=0; stores
//         h_fin[16] and sum(dt) (decay product = exp(A*sum_dt)).
// Grid: B * PCH * (D_INNER/256) = 512 blocks. Consecutive tid = consecutive d
// -> all dt/u loads coalesced; B loads wave-uniform (scalarized).
// ---------------------------------------------------------------------------
__global__ __launch_bounds__(256) void scan_pass1(
    const float* __restrict__ dtbuf,  // (B,S,D_INNER)
    const float* __restrict__ ubuf,   // (B,S,D_INNER)
    const float* __restrict__ dbl,    // (B,S,64) cols 32..47=B
    const float* __restrict__ A_log,  // (D_INNER,16)
    float* __restrict__ hfin,         // (B,PCH,16,D_INNER)
    float* __restrict__ sumdt)        // (B,PCH,D_INNER)
{
    const int tid = threadIdx.x;
    const int b = blockIdx.x >> 7;
    const int p = (blockIdx.x >> 2) & 31;
    const int d = ((blockIdx.x & 3) << 8) + tid;
    const int t0 = p * CLEN;

    float A[D_STATE];
    #pragma unroll
    for (int n = 0; n < D_STATE; n++) A[n] = -expf(A_log[d * D_STATE + n]);

    float h[D_STATE] = {};
    float sdt = 0.f;

    const float* dtp = dtbuf + ((size_t)b * SEQ + t0) * D_INNER + d;
    const float* up  = ubuf  + ((size_t)b * SEQ + t0) * D_INNER + d;
    const float* bp  = dbl   + ((size_t)b * SEQ + t0) * 64 + 32;

    for (int t = 0; t < CLEN; t++) {
        float dtv = dtp[(size_t)t * D_INNER];
        float uv  = up[(size_t)t * D_INNER];
        float dtu = dtv * uv;
        sdt += dtv;
        #pragma unroll
        for (int n = 0; n < D_STATE; n++) {
            float Bv = bp[t * 64 + n];       // wave-uniform
            h[n] = fmaf(__expf(dtv * A[n]), h[n], dtu * Bv);
        }
    }

    size_t base = (size_t)(b * PCH + p) * D_STATE * D_INNER + d;
    #pragma unroll
    for (int n = 0; n < D_STATE; n++) hfin[base + (size_t)n * D_INNER] = h[n];
    sumdt[(size_t)(b * PCH + p) * D_INNER + d] = sdt;
}

// ---------------------------------------------------------------------------
// Pass 2: sequential carry across PCH=32 chunks, in place.
// hc holds h_fin on entry; on exit holds the chunk START state.
// Thread per (b, n, d): grid B*16*(D_INNER/256) = 256 blocks.
// ---------------------------------------------------------------------------
__global__ __launch_bounds__(256) void scan_pass2(
    const float* __restrict__ A_log,
    const float* __restrict__ sumdt,
    float* __restrict__ hc)
{
    const int tid = threadIdx.x;
    const int b = blockIdx.x >> 6;
    const int n = (blockIdx.x >> 2) & 15;
    const int d = ((blockIdx.x & 3) << 8) + tid;

    const float Aval = -expf(A_log[d * D_STATE + n]);
    float h = 0.f;
    for (int p = 0; p < PCH; p++) {
        size_t idx = ((size_t)(b * PCH + p) * D_STATE + n) * D_INNER + d;
        float fin = hc[idx];
        hc[idx] = h;  // start state for chunk p
        h = fmaf(__expf(Aval * sumdt[(size_t)(b * PCH + p) * D_INNER + d]), h, fin);
    }
}

// ---------------------------------------------------------------------------
// Pass 3: re-run each chunk from its correct start state, compute
// y = sum_n h[n]*C[n] + u*D, fuse gate y *= silu(z). Overwrites ubuf.
// ---------------------------------------------------------------------------
__global__ __launch_bounds__(256) void scan_pass3(
    const float* __restrict__ dtbuf,
    const float* __restrict__ dbl,
    const float* __restrict__ xz,     // z = cols D_INNER..2*D_INNER
    const float* __restrict__ A_log,
    const float* __restrict__ Dp,
    const float* __restrict__ hstart, // (B,PCH,16,D_INNER)
    float* __restrict__ ubuf)         // in: u, out: y*silu(z)
{
    const int tid = threadIdx.x;
    const int b = blockIdx.x >> 7;
    const int p = (blockIdx.x >> 2) & 31;
    const int d = ((blockIdx.x & 3) << 8) + tid;
    const int t0 = p * CLEN;

    float A[D_STATE];
    #pragma unroll
    for (int n = 0; n < D_STATE; n++) A[n] = -expf(A_log[d * D_STATE + n]);
    const float Dv = Dp[d];

    float h[D_STATE];
    size_t base = (size_t)(b * PCH + p) * D_STATE * D_INNER + d;
    #pragma unroll
    for (int n = 0; n < D_STATE; n++) h[n] = hstart[base + (size_t)n * D_INNER];

    const float* dtp = dtbuf + ((size_t)b * SEQ + t0) * D_INNER + d;
    float* up        = ubuf  + ((size_t)b * SEQ + t0) * D_INNER + d;
    const float* zp  = xz + ((size_t)b * SEQ + t0) * (2 * D_INNER) + D_INNER + d;
    const float* bp  = dbl + ((size_t)b * SEQ + t0) * 64 + 32;

    for (int t = 0; t < CLEN; t++) {
        float dtv = dtp[(size_t)t * D_INNER];
        float uv  = up[(size_t)t * D_INNER];
        float zv  = zp[(size_t)t * (2 * D_INNER)];
        float dtu = dtv * uv;
        float y = 0.f;
        #pragma unroll
        for (int n = 0; n < D_STATE; n++) {
            float Bv = bp[t * 64 + n];
            float Cv = bp[t * 64 + 16 + n];
            h[n] = fmaf(__expf(dtv * A[n]), h[n], dtu * Bv);
            y = fmaf(h[n], Cv, y);
        }
        float res = fmaf(uv, Dv, y);
        res *= zv / (1.f + __expf(-zv));   // fused gate
        up[(size_t)t * D_INNER] = res;
    }
}

// ---------------------------------------------------------------------------
// Grouped softmax over last-dim groups of 32 (N_CAT).
// ---------------------------------------------------------------------------
__global__ __launch_bounds__(256) void softmax_kernel(
    const float* __restrict__ in, float* __restrict__ out)
{
    const int idx = blockIdx.x * 256 + threadIdx.x;
    float v = in[idx];
    float m = v;
    #pragma unroll
    for (int off = 16; off > 0; off >>= 1) m = fmaxf(m, __shfl_xor(m, off, 32));
    float e = expf(v - m);
    float s = e;
    #pragma unroll
    for (int off = 16; off > 0; off >>= 1) s += __shfl_xor(s, off, 32);
    out[idx] = e / s;
}

// ---------------------------------------------------------------------------
extern "C" void kernel_launch(void* const* d_in, const int* in_sizes, int n_in,
                              void* d_out, int out_size, void* d_ws, size_t ws_size,
                              hipStream_t stream)
{
    const float* x       = (const float*)d_in[0];
    const float* lin1_w  = (const float*)d_in[1];
    const float* lin1_b  = (const float*)d_in[2];
    const float* norm_w  = (const float*)d_in[3];
    const float* in_w    = (const float*)d_in[4];
    const float* conv_w  = (const float*)d_in[5];
    const float* conv_b  = (const float*)d_in[6];
    const float* xproj_w = (const float*)d_in[7];
    const float* dt_w    = (const float*)d_in[8];
    const float* dt_b    = (const float*)d_in[9];
    const float* A_log   = (const float*)d_in[10];
    const float* Dp      = (const float*)d_in[11];
    const float* out_w   = (const float*)d_in[12];
    const float* lin2_w  = (const float*)d_in[13];
    const float* lin2_b  = (const float*)d_in[14];
    float* outp = (float*)d_out;

    float* ws = (float*)d_ws;
    const size_t SZ_H  = (size_t)NTOK * D_MODEL;      // 2M floats
    const size_t SZ_XZ = (size_t)NTOK * 2 * D_INNER;  // 8M
    const size_t SZ_XC = (size_t)NTOK * D_INNER;      // 4M
    const size_t SZ_DBL = (size_t)NTOK * 64;          // 256K

    float* h    = ws;
    float* hn   = h + SZ_H;      // dead after in-proj GEMM -> reused as hfin
    float* xz   = hn + SZ_H;
    float* xc   = xz + SZ_XZ;
    float* dbl  = xc + SZ_XC;
    float* dt   = dbl + SZ_DBL;
    float* sumdt = dt + SZ_XC;   // B*PCH*D_INNER = 128K floats
    // hfin aliases hn: B*PCH*16*D_INNER = 2M floats == SZ_H exactly.
    float* hfin = hn;
    (void)ws_size; (void)in_sizes; (void)n_in; (void)out_size;

    dim3 blk(256);

    // lin1: h = x @ lin1_w + lin1_b
    gemm_kernel<<<dim3(D_MODEL / 64, NTOK / 64), blk, 0, stream>>>(
        x, LATENT, lin1_w, D_MODEL, h, D_MODEL, lin1_b,
        NTOK, D_MODEL, LATENT, 1);

    for (int l = 0; l < N_LAYERS; l++) {
        const float* nw  = norm_w + (size_t)l * D_MODEL;
        const float* iw  = in_w + (size_t)l * D_MODEL * 2 * D_INNER;
        const float* cw  = conv_w + (size_t)l * D_INNER * KCONV;
        const float* cb  = conv_b + (size_t)l * D_INNER;
        const float* xw  = xproj_w + (size_t)l * D_INNER * (DT_RANK + 2 * D_STATE);
        const float* dw  = dt_w + (size_t)l * DT_RANK * D_INNER;
        const float* db  = dt_b + (size_t)l * D_INNER;
        const float* al  = A_log + (size_t)l * D_INNER * D_STATE;
        const float* dp  = Dp + (size_t)l * D_INNER;
        const float* ow  = out_w + (size_t)l * D_INNER * D_MODEL;

        rmsnorm_kernel<<<dim3(NTOK), blk, 0, stream>>>(h, nw, hn);

        // xz = hn @ in_w[l]   (hn dead after this)
        gemm_kernel<<<dim3((2 * D_INNER) / 64, NTOK / 64), blk, 0, stream>>>(
            hn, D_MODEL, iw, 2 * D_INNER, xz, 2 * D_INNER, nullptr,
            NTOK, 2 * D_INNER, D_MODEL, 0);

        // xc = silu(conv(xz[:, :D_INNER]) + conv_b)
        conv_silu_kernel<<<dim3((NTOK * D_INNER) / 256), blk, 0, stream>>>(
            xz, cw, cb, xc);

        // dbl = xc @ xproj_w[l]
        gemm_kernel<<<dim3(64 / 64, NTOK / 64), blk, 0, stream>>>(
            xc, D_INNER, xw, 64, dbl, 64, nullptr,
            NTOK, 64, D_INNER, 0);

        // dt = softplus(dbl[:, :32] @ dt_w[l] + dt_b[l])
        gemm_kernel<<<dim3(D_INNER / 64, NTOK / 64), blk, 0, stream>>>(
            dbl, 64, dw, D_INNER, dt, D_INNER, db,
            NTOK, D_INNER, DT_RANK, 1 | 4);

        // chunked selective scan (3 passes) + fused gate: xc -> y*silu(z)
        scan_pass1<<<dim3(BATCH * PCH * (D_INNER / 256)), blk, 0, stream>>>(
            dt, xc, dbl, al, hfin, sumdt);
        scan_pass2<<<dim3(BATCH * D_STATE * (D_INNER / 256)), blk, 0, stream>>>(
            al, sumdt, hfin);
        scan_pass3<<<dim3(BATCH * PCH * (D_INNER / 256)), blk, 0, stream>>>(
            dt, dbl, xz, al, dp, hfin, xc);

        // h += y @ out_w[l]
        gemm_kernel<<<dim3(D_MODEL / 64, NTOK / 64), blk, 0, stream>>>(
            xc, D_INNER, ow, D_MODEL, h, D_MODEL, nullptr,
            NTOK, D_MODEL, D_INNER, 2);
    }

    // logits (reuse xz) = h @ lin2_w + lin2_b
    gemm_kernel<<<dim3(LATENT / 64, NTOK / 64), blk, 0, stream>>>(
        h, D_MODEL, lin2_w, LATENT, xz, LATENT, lin2_b,
        NTOK, LATENT, D_MODEL, 1);

    softmax_kernel<<<dim3((NTOK * LATENT) / 256), blk, 0, stream>>>(xz, outp);
}

// Round 4
// 1133.208 us; speedup vs baseline: 4.0118x; 1.4676x over previous
//
#include <hip/hip_runtime.h>
#include <math.h>

#define D_MODEL 512
#define N_LAYERS 4
#define LATENT 1024
#define D_INNER 1024
#define D_STATE 16
#define DT_RANK 32
#define KCONV 4
#define BATCH 4
#define SEQ 1024
#define NTOK (BATCH * SEQ) /* 4096 */
#define PCH 32
#define CLEN 32

typedef __attribute__((ext_vector_type(8))) short short8;
typedef __attribute__((ext_vector_type(4))) float floatx4;
typedef unsigned short ushort_t;

__device__ __forceinline__ ushort_t f2bf(float f) {
    union { float f; unsigned u; } v; v.f = f;
    unsigned r = v.u + 0x7FFFu + ((v.u >> 16) & 1u);  // RNE
    return (ushort_t)(r >> 16);
}

// ---------------------------------------------------------------------------
// bf16 MFMA GEMM: C[M,N] = A[M,K](bf16) @ Bt[N,K](bf16)^T (+bias)(+C)
// flags: 1 = add bias[n], 2 = accumulate into C.
// BM=BN=128, BK=32, 256 threads (4 waves), each wave 64x64 via 4x4 MFMAs.
// LDS rows padded 32->40 bf16 (80 B) => ds_read_b128 at <=2-way conflict.
// ---------------------------------------------------------------------------
__global__ __launch_bounds__(256) void gemm_bf16_kernel(
    const ushort_t* __restrict__ A, int lda,
    const ushort_t* __restrict__ Bt, int ldb,
    float* __restrict__ C, int ldc,
    const float* __restrict__ bias,
    int M, int N, int K, int flags)
{
    __shared__ ushort_t As[128][40];
    __shared__ ushort_t Bs[128][40];
    const int tid = threadIdx.x;
    const int m0 = blockIdx.y * 128;
    const int n0 = blockIdx.x * 128;
    const int w = tid >> 6;
    const int lane = tid & 63;
    const int quad = lane >> 4;
    const int l16 = lane & 15;
    const int wm = (w & 1) * 64;
    const int wn = (w >> 1) * 64;

    const int r = tid >> 2;
    const int c = (tid & 3) << 3;

    floatx4 acc[4][4] = {};

    for (int k0 = 0; k0 < K; k0 += 32) {
        __syncthreads();
        *(uint4*)&As[r][c]      = *(const uint4*)&A[(size_t)(m0 + r) * lda + k0 + c];
        *(uint4*)&As[r + 64][c] = *(const uint4*)&A[(size_t)(m0 + r + 64) * lda + k0 + c];
        *(uint4*)&Bs[r][c]      = *(const uint4*)&Bt[(size_t)(n0 + r) * ldb + k0 + c];
        *(uint4*)&Bs[r + 64][c] = *(const uint4*)&Bt[(size_t)(n0 + r + 64) * ldb + k0 + c];
        __syncthreads();

        short8 af[4], bfr[4];
        #pragma unroll
        for (int i = 0; i < 4; i++)
            af[i] = *(const short8*)&As[wm + i * 16 + l16][quad * 8];
        #pragma unroll
        for (int j = 0; j < 4; j++)
            bfr[j] = *(const short8*)&Bs[wn + j * 16 + l16][quad * 8];
        #pragma unroll
        for (int i = 0; i < 4; i++)
            #pragma unroll
            for (int j = 0; j < 4; j++)
                acc[i][j] = __builtin_amdgcn_mfma_f32_16x16x32_bf16(
                    af[i], bfr[j], acc[i][j], 0, 0, 0);
    }

    // C/D layout (m89-verified): col = lane&15, row = quad*4 + reg.
    #pragma unroll
    for (int j = 0; j < 4; j++) {
        int n = n0 + wn + j * 16 + l16;
        float bv = (flags & 1) ? bias[n] : 0.f;
        #pragma unroll
        for (int i = 0; i < 4; i++) {
            int mrow = m0 + wm + i * 16 + quad * 4;
            #pragma unroll
            for (int rr = 0; rr < 4; rr++) {
                size_t idx = (size_t)(mrow + rr) * ldc + n;
                float v = acc[i][j][rr] + bv;
                if (flags & 2) v += C[idx];
                C[idx] = v;
            }
        }
    }
}

// ---------------------------------------------------------------------------
// fp32 tiled GEMM (kept for xproj N=64 and dt K=32).
// flags: 1=bias, 2=accumulate, 4=softplus
// ---------------------------------------------------------------------------
__global__ __launch_bounds__(256) void gemm_kernel(
    const float* __restrict__ A, int lda,
    const float* __restrict__ B, int ldb,
    float* __restrict__ C, int ldc,
    const float* __restrict__ bias,
    int M, int N, int K, int flags)
{
    const int BM = 64, BN = 64, BK = 16;
    __shared__ float As[16][68];
    __shared__ float Bs[16][68];

    const int tid = threadIdx.x;
    const int tx = tid & 15;
    const int ty = tid >> 4;
    const int m0 = blockIdx.y * BM;
    const int n0 = blockIdx.x * BN;

    float acc[4][4] = {};

    for (int k0 = 0; k0 < K; k0 += BK) {
        #pragma unroll
        for (int i = 0; i < (BM * BK) / 256; i++) {
            int idx = tid + i * 256;
            int rr = idx >> 4, cc = idx & 15;
            As[cc][rr] = A[(size_t)(m0 + rr) * lda + k0 + cc];
        }
        #pragma unroll
        for (int i = 0; i < (BK * BN) / 256; i++) {
            int idx = tid + i * 256;
            int rr = idx >> 6, cc = idx & 63;
            Bs[rr][cc] = B[(size_t)(k0 + rr) * ldb + n0 + cc];
        }
        __syncthreads();

        #pragma unroll
        for (int kk = 0; kk < BK; kk++) {
            float a[4], b[4];
            #pragma unroll
            for (int i = 0; i < 4; i++) a[i] = As[kk][ty * 4 + i];
            #pragma unroll
            for (int j = 0; j < 4; j++) b[j] = Bs[kk][tx * 4 + j];
            #pragma unroll
            for (int i = 0; i < 4; i++)
                #pragma unroll
                for (int j = 0; j < 4; j++)
                    acc[i][j] = fmaf(a[i], b[j], acc[i][j]);
        }
        __syncthreads();
    }

    #pragma unroll
    for (int i = 0; i < 4; i++) {
        int m = m0 + ty * 4 + i;
        #pragma unroll
        for (int j = 0; j < 4; j++) {
            int n = n0 + tx * 4 + j;
            float v = acc[i][j];
            if (flags & 1) v += bias[n];
            if (flags & 2) v += C[(size_t)m * ldc + n];
            if (flags & 4) v = (v > 20.f) ? v : log1pf(expf(v));
            C[(size_t)m * ldc + n] = v;
        }
    }
}

// ---------------------------------------------------------------------------
// Transpose-cast: fp32 [K][N] -> bf16 [N][K]. 32x32 tiles, 256 threads.
// ---------------------------------------------------------------------------
__global__ __launch_bounds__(256) void transpose_cast_kernel(
    const float* __restrict__ in, ushort_t* __restrict__ out, int K, int N)
{
    __shared__ float tile[32][33];
    const int n0 = blockIdx.x * 32, k0 = blockIdx.y * 32;
    const int tx = threadIdx.x & 31, ty = threadIdx.x >> 5;
    #pragma unroll
    for (int i = 0; i < 4; i++)
        tile[ty + i * 8][tx] = in[(size_t)(k0 + ty + i * 8) * N + n0 + tx];
    __syncthreads();
    #pragma unroll
    for (int i = 0; i < 4; i++)
        out[(size_t)(n0 + ty + i * 8) * K + k0 + tx] = f2bf(tile[tx][ty + i * 8]);
}

// ---------------------------------------------------------------------------
__global__ __launch_bounds__(256) void cast_bf16_kernel(
    const float* __restrict__ in, ushort_t* __restrict__ out)
{
    const int i = blockIdx.x * 256 + threadIdx.x;
    out[i] = f2bf(in[i]);
}

// ---------------------------------------------------------------------------
// RMSNorm over rows of D_MODEL=512, bf16 output. One block per row.
// ---------------------------------------------------------------------------
__global__ __launch_bounds__(256) void rmsnorm_kernel(
    const float* __restrict__ x, const float* __restrict__ w,
    ushort_t* __restrict__ y)
{
    const int row = blockIdx.x;
    const float* xr = x + (size_t)row * D_MODEL;
    ushort_t* yr = y + (size_t)row * D_MODEL;
    const int tid = threadIdx.x;

    float v0 = xr[tid], v1 = xr[tid + 256];
    float ss = v0 * v0 + v1 * v1;
    #pragma unroll
    for (int off = 32; off > 0; off >>= 1) ss += __shfl_down(ss, off);

    __shared__ float wsum[4];
    __shared__ float scale_s;
    int wid = tid >> 6, lane = tid & 63;
    if (lane == 0) wsum[wid] = ss;
    __syncthreads();
    if (tid == 0) {
        float tot = wsum[0] + wsum[1] + wsum[2] + wsum[3];
        scale_s = 1.0f / sqrtf(tot / (float)D_MODEL + 1e-5f);
    }
    __syncthreads();
    float sc = scale_s;
    yr[tid] = f2bf(v0 * sc * w[tid]);
    yr[tid + 256] = f2bf(v1 * sc * w[tid + 256]);
}

// ---------------------------------------------------------------------------
// Causal dwconv (K=4) + bias + silu.  In: xp (B,S,D_INNER). Out: xc.
// ---------------------------------------------------------------------------
__global__ __launch_bounds__(256) void conv_silu_kernel(
    const float* __restrict__ xp, const float* __restrict__ w,
    const float* __restrict__ bconv, float* __restrict__ out)
{
    const int idx = blockIdx.x * 256 + threadIdx.x;
    const int d = idx & (D_INNER - 1);
    const int t = (idx >> 10) & (SEQ - 1);

    float s = 0.f;
    #pragma unroll
    for (int k = 0; k < KCONV; k++) {
        int tt = t + k - (KCONV - 1);
        if (tt >= 0) s = fmaf(xp[idx + (k - (KCONV - 1)) * D_INNER], w[d * KCONV + k], s);
    }
    s += bconv[d];
    out[idx] = s / (1.f + __expf(-s));
}

// ---------------------------------------------------------------------------
// Chunked selective scan (3 passes), CLEN=32.
// ---------------------------------------------------------------------------
__global__ __launch_bounds__(256) void scan_pass1(
    const float* __restrict__ dtbuf, const float* __restrict__ ubuf,
    const float* __restrict__ dbl, const float* __restrict__ A_log,
    float* __restrict__ hfin, float* __restrict__ sumdt)
{
    const int tid = threadIdx.x;
    const int b = blockIdx.x >> 7;
    const int p = (blockIdx.x >> 2) & 31;
    const int d = ((blockIdx.x & 3) << 8) + tid;
    const int t0 = p * CLEN;

    float A[D_STATE];
    #pragma unroll
    for (int n = 0; n < D_STATE; n++) A[n] = -expf(A_log[d * D_STATE + n]);

    float h[D_STATE] = {};
    float sdt = 0.f;

    const float* dtp = dtbuf + ((size_t)b * SEQ + t0) * D_INNER + d;
    const float* up  = ubuf  + ((size_t)b * SEQ + t0) * D_INNER + d;
    const float* bp  = dbl   + ((size_t)b * SEQ + t0) * 64 + 32;

    for (int t = 0; t < CLEN; t++) {
        float dtv = dtp[(size_t)t * D_INNER];
        float uv  = up[(size_t)t * D_INNER];
        float dtu = dtv * uv;
        sdt += dtv;
        #pragma unroll
        for (int n = 0; n < D_STATE; n++)
            h[n] = fmaf(__expf(dtv * A[n]), h[n], dtu * bp[t * 64 + n]);
    }

    size_t base = (size_t)(b * PCH + p) * D_STATE * D_INNER + d;
    #pragma unroll
    for (int n = 0; n < D_STATE; n++) hfin[base + (size_t)n * D_INNER] = h[n];
    sumdt[(size_t)(b * PCH + p) * D_INNER + d] = sdt;
}

__global__ __launch_bounds__(256) void scan_pass2(
    const float* __restrict__ A_log, const float* __restrict__ sumdt,
    float* __restrict__ hc)
{
    const int tid = threadIdx.x;
    const int b = blockIdx.x >> 6;
    const int n = (blockIdx.x >> 2) & 15;
    const int d = ((blockIdx.x & 3) << 8) + tid;

    const float Aval = -expf(A_log[d * D_STATE + n]);
    float h = 0.f;
    for (int p = 0; p < PCH; p++) {
        size_t idx = ((size_t)(b * PCH + p) * D_STATE + n) * D_INNER + d;
        float fin = hc[idx];
        hc[idx] = h;
        h = fmaf(__expf(Aval * sumdt[(size_t)(b * PCH + p) * D_INNER + d]), h, fin);
    }
}

__global__ __launch_bounds__(256) void scan_pass3(
    const float* __restrict__ dtbuf, const float* __restrict__ dbl,
    const float* __restrict__ zbuf, const float* __restrict__ A_log,
    const float* __restrict__ Dp, const float* __restrict__ hstart,
    const float* __restrict__ ubuf, ushort_t* __restrict__ yout)
{
    const int tid = threadIdx.x;
    const int b = blockIdx.x >> 7;
    const int p = (blockIdx.x >> 2) & 31;
    const int d = ((blockIdx.x & 3) << 8) + tid;
    const int t0 = p * CLEN;

    float A[D_STATE];
    #pragma unroll
    for (int n = 0; n < D_STATE; n++) A[n] = -expf(A_log[d * D_STATE + n]);
    const float Dv = Dp[d];

    float h[D_STATE];
    size_t base = (size_t)(b * PCH + p) * D_STATE * D_INNER + d;
    #pragma unroll
    for (int n = 0; n < D_STATE; n++) h[n] = hstart[base + (size_t)n * D_INNER];

    const size_t off0 = ((size_t)b * SEQ + t0) * D_INNER + d;
    const float* dtp = dtbuf + off0;
    const float* up  = ubuf + off0;
    const float* zp  = zbuf + off0;
    ushort_t* yp     = yout + off0;
    const float* bp  = dbl + ((size_t)b * SEQ + t0) * 64 + 32;

    for (int t = 0; t < CLEN; t++) {
        float dtv = dtp[(size_t)t * D_INNER];
        float uv  = up[(size_t)t * D_INNER];
        float zv  = zp[(size_t)t * D_INNER];
        float dtu = dtv * uv;
        float y = 0.f;
        #pragma unroll
        for (int n = 0; n < D_STATE; n++) {
            h[n] = fmaf(__expf(dtv * A[n]), h[n], dtu * bp[t * 64 + n]);
            y = fmaf(h[n], bp[t * 64 + 16 + n], y);
        }
        float res = fmaf(uv, Dv, y);
        res *= zv / (1.f + __expf(-zv));
        yp[(size_t)t * D_INNER] = f2bf(res);
    }
}

// ---------------------------------------------------------------------------
__global__ __launch_bounds__(256) void softmax_kernel(
    const float* __restrict__ in, float* __restrict__ out)
{
    const int idx = blockIdx.x * 256 + threadIdx.x;
    float v = in[idx];
    float m = v;
    #pragma unroll
    for (int off = 16; off > 0; off >>= 1) m = fmaxf(m, __shfl_xor(m, off, 32));
    float e = expf(v - m);
    float s = e;
    #pragma unroll
    for (int off = 16; off > 0; off >>= 1) s += __shfl_xor(s, off, 32);
    out[idx] = e / s;
}

// ---------------------------------------------------------------------------
extern "C" void kernel_launch(void* const* d_in, const int* in_sizes, int n_in,
                              void* d_out, int out_size, void* d_ws, size_t ws_size,
                              hipStream_t stream)
{
    const float* x       = (const float*)d_in[0];
    const float* lin1_w  = (const float*)d_in[1];
    const float* lin1_b  = (const float*)d_in[2];
    const float* norm_w  = (const float*)d_in[3];
    const float* in_w    = (const float*)d_in[4];
    const float* conv_w  = (const float*)d_in[5];
    const float* conv_b  = (const float*)d_in[6];
    const float* xproj_w = (const float*)d_in[7];
    const float* dt_w    = (const float*)d_in[8];
    const float* dt_b    = (const float*)d_in[9];
    const float* A_log   = (const float*)d_in[10];
    const float* Dp      = (const float*)d_in[11];
    const float* out_w   = (const float*)d_in[12];
    const float* lin2_w  = (const float*)d_in[13];
    const float* lin2_b  = (const float*)d_in[14];
    float* outp = (float*)d_out;
    (void)ws_size; (void)in_sizes; (void)n_in; (void)out_size;

    float* ws = (float*)d_ws;
    const size_t F1M = 1u << 20;
    float* h     = ws;                 // 2M floats
    float* xp    = h + 2 * F1M;        // 4M (aliased as hfin after conv)
    float* z     = xp + 4 * F1M;       // 4M
    float* xc    = z + 4 * F1M;        // 4M
    float* dbl   = xc + 4 * F1M;       // 256K
    float* dt    = dbl + (NTOK * 64);  // 4M
    float* sumdt = dt + 4 * F1M;       // 128K
    ushort_t* hn_bf = (ushort_t*)(sumdt + BATCH * PCH * D_INNER); // 2M us = 1M fl
    ushort_t* xb    = (ushort_t*)((float*)hn_bf + 1 * F1M);       // 4M us = 2M fl
    ushort_t* wt    = (ushort_t*)((float*)xb + 2 * F1M);          // 7M ushort
    ushort_t* lin1_wt = wt;                                   // 512*1024
    ushort_t* in_wt   = lin1_wt + (size_t)512 * 1024;         // 4*2048*512
    ushort_t* out_wt  = in_wt + (size_t)4 * 2048 * 512;       // 4*512*1024
    ushort_t* lin2_wt = out_wt + (size_t)4 * 512 * 1024;      // 1024*512
    float* hfin = xp;

    dim3 blk(256);

    // --- weight prep: transpose-cast fp32 [K][N] -> bf16 [N][K] ---
    transpose_cast_kernel<<<dim3(512 / 32, 1024 / 32), blk, 0, stream>>>(
        lin1_w, lin1_wt, LATENT, D_MODEL);
    for (int l = 0; l < N_LAYERS; l++) {
        transpose_cast_kernel<<<dim3(2048 / 32, 512 / 32), blk, 0, stream>>>(
            in_w + (size_t)l * 512 * 2048, in_wt + (size_t)l * 2048 * 512, 512, 2048);
        transpose_cast_kernel<<<dim3(512 / 32, 1024 / 32), blk, 0, stream>>>(
            out_w + (size_t)l * 1024 * 512, out_wt + (size_t)l * 512 * 1024, 1024, 512);
    }
    transpose_cast_kernel<<<dim3(1024 / 32, 512 / 32), blk, 0, stream>>>(
        lin2_w, lin2_wt, D_MODEL, LATENT);

    // x -> bf16
    cast_bf16_kernel<<<dim3((NTOK * LATENT) / 256), blk, 0, stream>>>(x, xb);

    // lin1: h = x_bf @ lin1_wt^T + b
    gemm_bf16_kernel<<<dim3(D_MODEL / 128, NTOK / 128), blk, 0, stream>>>(
        xb, LATENT, lin1_wt, LATENT, h, D_MODEL, lin1_b,
        NTOK, D_MODEL, LATENT, 1);

    for (int l = 0; l < N_LAYERS; l++) {
        const float* nw = norm_w + (size_t)l * D_MODEL;
        const float* cw = conv_w + (size_t)l * D_INNER * KCONV;
        const float* cb = conv_b + (size_t)l * D_INNER;
        const float* xw = xproj_w + (size_t)l * D_INNER * 64;
        const float* dw = dt_w + (size_t)l * DT_RANK * D_INNER;
        const float* db = dt_b + (size_t)l * D_INNER;
        const float* al = A_log + (size_t)l * D_INNER * D_STATE;
        const float* dp = Dp + (size_t)l * D_INNER;
        const ushort_t* iwt = in_wt + (size_t)l * 2048 * 512;
        const ushort_t* owt = out_wt + (size_t)l * 512 * 1024;

        rmsnorm_kernel<<<dim3(NTOK), blk, 0, stream>>>(h, nw, hn_bf);

        // in-proj split: xp = hn@W[:, :1024], z = hn@W[:, 1024:]
        gemm_bf16_kernel<<<dim3(D_INNER / 128, NTOK / 128), blk, 0, stream>>>(
            hn_bf, D_MODEL, iwt, D_MODEL, xp, D_INNER, nullptr,
            NTOK, D_INNER, D_MODEL, 0);
        gemm_bf16_kernel<<<dim3(D_INNER / 128, NTOK / 128), blk, 0, stream>>>(
            hn_bf, D_MODEL, iwt + (size_t)1024 * 512, D_MODEL, z, D_INNER, nullptr,
            NTOK, D_INNER, D_MODEL, 0);

        conv_silu_kernel<<<dim3((NTOK * D_INNER) / 256), blk, 0, stream>>>(
            xp, cw, cb, xc);

        // dbl = xc @ xproj_w[l]  (fp32, N=64)
        gemm_kernel<<<dim3(1, NTOK / 64), blk, 0, stream>>>(
            xc, D_INNER, xw, 64, dbl, 64, nullptr,
            NTOK, 64, D_INNER, 0);

        // dt = softplus(dbl[:, :32] @ dt_w + dt_b)  (fp32, K=32)
        gemm_kernel<<<dim3(D_INNER / 64, NTOK / 64), blk, 0, stream>>>(
            dbl, 64, dw, D_INNER, dt, D_INNER, db,
            NTOK, D_INNER, DT_RANK, 1 | 4);

        // chunked scan (hfin aliases xp, dead after conv)
        scan_pass1<<<dim3(BATCH * PCH * (D_INNER / 256)), blk, 0, stream>>>(
            dt, xc, dbl, al, hfin, sumdt);
        scan_pass2<<<dim3(BATCH * D_STATE * (D_INNER / 256)), blk, 0, stream>>>(
            al, sumdt, hfin);
        scan_pass3<<<dim3(BATCH * PCH * (D_INNER / 256)), blk, 0, stream>>>(
            dt, dbl, z, al, dp, hfin, xc, xb);

        // h += y_bf @ out_wt^T
        gemm_bf16_kernel<<<dim3(D_MODEL / 128, NTOK / 128), blk, 0, stream>>>(
            xb, D_INNER, owt, D_INNER, h, D_MODEL, nullptr,
            NTOK, D_MODEL, D_INNER, 2);
    }

    // h -> bf16, lin2, softmax
    cast_bf16_kernel<<<dim3((NTOK * D_MODEL) / 256), blk, 0, stream>>>(h, xb);
    gemm_bf16_kernel<<<dim3(LATENT / 128, NTOK / 128), blk, 0, stream>>>(
        xb, D_MODEL, lin2_wt, D_MODEL, xp, LATENT, lin2_b,
        NTOK, LATENT, D_MODEL, 1);
    softmax_kernel<<<dim3((NTOK * LATENT) / 256), blk, 0, stream>>>(xp, outp);
}

// Round 5
// 1088.892 us; speedup vs baseline: 4.1750x; 1.0407x over previous
//
#include <hip/hip_runtime.h>
#include <math.h>

#define D_MODEL 512
#define N_LAYERS 4
#define LATENT 1024
#define D_INNER 1024
#define D_STATE 16
#define DT_RANK 32
#define KCONV 4
#define BATCH 4
#define SEQ 1024
#define NTOK (BATCH * SEQ) /* 4096 */
#define PCH 32
#define CLEN 32
#define NCAT 1152  /* merged xproj+dt GEMM N: 1024 dt | 32 B/C | 96 pad */

typedef __attribute__((ext_vector_type(8))) short short8;
typedef __attribute__((ext_vector_type(4))) float floatx4;
typedef unsigned short ushort_t;

__device__ __forceinline__ ushort_t f2bf(float f) {
    union { float f; unsigned u; } v; v.f = f;
    unsigned r = v.u + 0x7FFFu + ((v.u >> 16) & 1u);  // RNE
    return (ushort_t)(r >> 16);
}

// ---------------------------------------------------------------------------
// bf16 MFMA GEMM: C[M,N] = A[M,K](bf16) @ Bt[N,K](bf16)^T (+bias)(+C)
// flags: 1 = add bias[n], 2 = accumulate into C,
//        4 = merged-dt epilogue: for n<1024 only, v = softplus(v + bias[n]).
// BM=BN=128, BK=32, 256 threads (4 waves), each wave 64x64 via 4x4 MFMAs.
// ---------------------------------------------------------------------------
__global__ __launch_bounds__(256) void gemm_bf16_kernel(
    const ushort_t* __restrict__ A, int lda,
    const ushort_t* __restrict__ Bt, int ldb,
    float* __restrict__ C, int ldc,
    const float* __restrict__ bias,
    int M, int N, int K, int flags)
{
    __shared__ ushort_t As[128][40];
    __shared__ ushort_t Bs[128][40];
    const int tid = threadIdx.x;
    const int m0 = blockIdx.y * 128;
    const int n0 = blockIdx.x * 128;
    const int w = tid >> 6;
    const int lane = tid & 63;
    const int quad = lane >> 4;
    const int l16 = lane & 15;
    const int wm = (w & 1) * 64;
    const int wn = (w >> 1) * 64;

    const int r = tid >> 2;
    const int c = (tid & 3) << 3;

    floatx4 acc[4][4] = {};

    for (int k0 = 0; k0 < K; k0 += 32) {
        __syncthreads();
        *(uint4*)&As[r][c]      = *(const uint4*)&A[(size_t)(m0 + r) * lda + k0 + c];
        *(uint4*)&As[r + 64][c] = *(const uint4*)&A[(size_t)(m0 + r + 64) * lda + k0 + c];
        *(uint4*)&Bs[r][c]      = *(const uint4*)&Bt[(size_t)(n0 + r) * ldb + k0 + c];
        *(uint4*)&Bs[r + 64][c] = *(const uint4*)&Bt[(size_t)(n0 + r + 64) * ldb + k0 + c];
        __syncthreads();

        short8 af[4], bfr[4];
        #pragma unroll
        for (int i = 0; i < 4; i++)
            af[i] = *(const short8*)&As[wm + i * 16 + l16][quad * 8];
        #pragma unroll
        for (int j = 0; j < 4; j++)
            bfr[j] = *(const short8*)&Bs[wn + j * 16 + l16][quad * 8];
        #pragma unroll
        for (int i = 0; i < 4; i++)
            #pragma unroll
            for (int j = 0; j < 4; j++)
                acc[i][j] = __builtin_amdgcn_mfma_f32_16x16x32_bf16(
                    af[i], bfr[j], acc[i][j], 0, 0, 0);
    }

    // C/D layout (m89-verified): col = lane&15, row = quad*4 + reg.
    #pragma unroll
    for (int j = 0; j < 4; j++) {
        int n = n0 + wn + j * 16 + l16;
        float bv = (flags & 1) ? bias[n] : 0.f;
        bool do_sp = (flags & 4) && (n < 1024);
        float spb = do_sp ? bias[n] : 0.f;
        #pragma unroll
        for (int i = 0; i < 4; i++) {
            int mrow = m0 + wm + i * 16 + quad * 4;
            #pragma unroll
            for (int rr = 0; rr < 4; rr++) {
                size_t idx = (size_t)(mrow + rr) * ldc + n;
                float v = acc[i][j][rr] + bv;
                if (do_sp) {
                    v += spb;
                    v = (v > 20.f) ? v : log1pf(__expf(v));
                }
                if (flags & 2) v += C[idx];
                C[idx] = v;
            }
        }
    }
}

// ---------------------------------------------------------------------------
// Build merged weight Wcat^T [NCAT][1024] bf16 per layer:
//   rows 0..1023   : (xw[:, :32] @ dt_w)^T      (the folded dt projection)
//   rows 1024..1055: xw[:, 32+j]^T              (B/C projection)
//   rows 1056..1151: zero pad
// grid (NCAT, N_LAYERS), 256 threads; thread handles 4 consecutive k.
// ---------------------------------------------------------------------------
__global__ __launch_bounds__(256) void build_wcat_kernel(
    const float* __restrict__ xproj_w, const float* __restrict__ dt_w,
    ushort_t* __restrict__ wcat)
{
    const int l = blockIdx.y;
    const int n = blockIdx.x;
    const int tid = threadIdx.x;
    const float* xw = xproj_w + (size_t)l * D_INNER * 64;
    ushort_t* out = wcat + ((size_t)l * NCAT + n) * D_INNER;
    const int k0 = tid * 4;

    ushort4 o;
    if (n < 1024) {
        __shared__ float dcol[DT_RANK];
        if (tid < DT_RANK)
            dcol[tid] = dt_w[((size_t)l * DT_RANK + tid) * D_INNER + n];
        __syncthreads();
        float acc[4] = {0.f, 0.f, 0.f, 0.f};
        #pragma unroll
        for (int q = 0; q < 4; q++) {
            const float4* xwr = (const float4*)(xw + (size_t)(k0 + q) * 64);
            #pragma unroll
            for (int r4 = 0; r4 < 8; r4++) {
                float4 v = xwr[r4];
                acc[q] = fmaf(v.x, dcol[r4 * 4 + 0], acc[q]);
                acc[q] = fmaf(v.y, dcol[r4 * 4 + 1], acc[q]);
                acc[q] = fmaf(v.z, dcol[r4 * 4 + 2], acc[q]);
                acc[q] = fmaf(v.w, dcol[r4 * 4 + 3], acc[q]);
            }
        }
        o.x = f2bf(acc[0]); o.y = f2bf(acc[1]);
        o.z = f2bf(acc[2]); o.w = f2bf(acc[3]);
    } else if (n < 1056) {
        int j = n - 1024 + 32;
        o.x = f2bf(xw[(size_t)(k0 + 0) * 64 + j]);
        o.y = f2bf(xw[(size_t)(k0 + 1) * 64 + j]);
        o.z = f2bf(xw[(size_t)(k0 + 2) * 64 + j]);
        o.w = f2bf(xw[(size_t)(k0 + 3) * 64 + j]);
    } else {
        o.x = o.y = o.z = o.w = 0;
    }
    *(ushort4*)&out[k0] = o;
}

// ---------------------------------------------------------------------------
// Transpose-cast: fp32 [K][N] -> bf16 [N][K]. 32x32 tiles, 256 threads.
// ---------------------------------------------------------------------------
__global__ __launch_bounds__(256) void transpose_cast_kernel(
    const float* __restrict__ in, ushort_t* __restrict__ out, int K, int N)
{
    __shared__ float tile[32][33];
    const int n0 = blockIdx.x * 32, k0 = blockIdx.y * 32;
    const int tx = threadIdx.x & 31, ty = threadIdx.x >> 5;
    #pragma unroll
    for (int i = 0; i < 4; i++)
        tile[ty + i * 8][tx] = in[(size_t)(k0 + ty + i * 8) * N + n0 + tx];
    __syncthreads();
    #pragma unroll
    for (int i = 0; i < 4; i++)
        out[(size_t)(n0 + ty + i * 8) * K + k0 + tx] = f2bf(tile[tx][ty + i * 8]);
}

// ---------------------------------------------------------------------------
__global__ __launch_bounds__(256) void cast_bf16_kernel(
    const float* __restrict__ in, ushort_t* __restrict__ out)
{
    const int i = blockIdx.x * 256 + threadIdx.x;
    out[i] = f2bf(in[i]);
}

// ---------------------------------------------------------------------------
// RMSNorm over rows of D_MODEL=512, bf16 output. One block per row.
// ---------------------------------------------------------------------------
__global__ __launch_bounds__(256) void rmsnorm_kernel(
    const float* __restrict__ x, const float* __restrict__ w,
    ushort_t* __restrict__ y)
{
    const int row = blockIdx.x;
    const float* xr = x + (size_t)row * D_MODEL;
    ushort_t* yr = y + (size_t)row * D_MODEL;
    const int tid = threadIdx.x;

    float v0 = xr[tid], v1 = xr[tid + 256];
    float ss = v0 * v0 + v1 * v1;
    #pragma unroll
    for (int off = 32; off > 0; off >>= 1) ss += __shfl_down(ss, off);

    __shared__ float wsum[4];
    __shared__ float scale_s;
    int wid = tid >> 6, lane = tid & 63;
    if (lane == 0) wsum[wid] = ss;
    __syncthreads();
    if (tid == 0) {
        float tot = wsum[0] + wsum[1] + wsum[2] + wsum[3];
        scale_s = 1.0f / sqrtf(tot / (float)D_MODEL + 1e-5f);
    }
    __syncthreads();
    float sc = scale_s;
    yr[tid] = f2bf(v0 * sc * w[tid]);
    yr[tid + 256] = f2bf(v1 * sc * w[tid + 256]);
}

// ---------------------------------------------------------------------------
// Causal dwconv (K=4) + bias + silu. Dual output: fp32 (for scan u) and
// bf16 (A-operand of the merged xproj/dt GEMM).
// ---------------------------------------------------------------------------
__global__ __launch_bounds__(256) void conv_silu_kernel(
    const float* __restrict__ xp, const float* __restrict__ w,
    const float* __restrict__ bconv, float* __restrict__ out,
    ushort_t* __restrict__ outb)
{
    const int idx = blockIdx.x * 256 + threadIdx.x;
    const int d = idx & (D_INNER - 1);
    const int t = (idx >> 10) & (SEQ - 1);

    float s = 0.f;
    #pragma unroll
    for (int k = 0; k < KCONV; k++) {
        int tt = t + k - (KCONV - 1);
        if (tt >= 0) s = fmaf(xp[idx + (k - (KCONV - 1)) * D_INNER], w[d * KCONV + k], s);
    }
    s += bconv[d];
    float r = s / (1.f + __expf(-s));
    out[idx] = r;
    outb[idx] = f2bf(r);
}

// ---------------------------------------------------------------------------
// Chunked selective scan (3 passes), CLEN=32.
// dt and B/C now live in the merged dbl buffer, row stride NCAT:
//   dbl[row][d]        = dt (d<1024, already softplus'ed)
//   dbl[row][1024+n]   = B[n],  dbl[row][1040+n] = C[n]
// ---------------------------------------------------------------------------
__global__ __launch_bounds__(256) void scan_pass1(
    const float* __restrict__ dbl, const float* __restrict__ ubuf,
    const float* __restrict__ A_log,
    float* __restrict__ hfin, float* __restrict__ sumdt)
{
    const int tid = threadIdx.x;
    const int b = blockIdx.x >> 7;
    const int p = (blockIdx.x >> 2) & 31;
    const int d = ((blockIdx.x & 3) << 8) + tid;
    const int t0 = p * CLEN;

    float A[D_STATE];
    #pragma unroll
    for (int n = 0; n < D_STATE; n++) A[n] = -expf(A_log[d * D_STATE + n]);

    float h[D_STATE] = {};
    float sdt = 0.f;

    const float* dtp = dbl + ((size_t)b * SEQ + t0) * NCAT + d;
    const float* bp  = dbl + ((size_t)b * SEQ + t0) * NCAT + 1024;
    const float* up  = ubuf + ((size_t)b * SEQ + t0) * D_INNER + d;

    for (int t = 0; t < CLEN; t++) {
        float dtv = dtp[(size_t)t * NCAT];
        float uv  = up[(size_t)t * D_INNER];
        float dtu = dtv * uv;
        sdt += dtv;
        #pragma unroll
        for (int n = 0; n < D_STATE; n++)
            h[n] = fmaf(__expf(dtv * A[n]), h[n], dtu * bp[t * NCAT + n]);
    }

    size_t base = (size_t)(b * PCH + p) * D_STATE * D_INNER + d;
    #pragma unroll
    for (int n = 0; n < D_STATE; n++) hfin[base + (size_t)n * D_INNER] = h[n];
    sumdt[(size_t)(b * PCH + p) * D_INNER + d] = sdt;
}

__global__ __launch_bounds__(256) void scan_pass2(
    const float* __restrict__ A_log, const float* __restrict__ sumdt,
    float* __restrict__ hc)
{
    const int tid = threadIdx.x;
    const int b = blockIdx.x >> 6;
    const int n = (blockIdx.x >> 2) & 15;
    const int d = ((blockIdx.x & 3) << 8) + tid;

    const float Aval = -expf(A_log[d * D_STATE + n]);
    float h = 0.f;
    for (int p = 0; p < PCH; p++) {
        size_t idx = ((size_t)(b * PCH + p) * D_STATE + n) * D_INNER + d;
        float fin = hc[idx];
        hc[idx] = h;
        h = fmaf(__expf(Aval * sumdt[(size_t)(b * PCH + p) * D_INNER + d]), h, fin);
    }
}

__global__ __launch_bounds__(256) void scan_pass3(
    const float* __restrict__ dbl, const float* __restrict__ zbuf,
    const float* __restrict__ A_log, const float* __restrict__ Dp,
    const float* __restrict__ hstart, const float* __restrict__ ubuf,
    ushort_t* __restrict__ yout)
{
    const int tid = threadIdx.x;
    const int b = blockIdx.x >> 7;
    const int p = (blockIdx.x >> 2) & 31;
    const int d = ((blockIdx.x & 3) << 8) + tid;
    const int t0 = p * CLEN;

    float A[D_STATE];
    #pragma unroll
    for (int n = 0; n < D_STATE; n++) A[n] = -expf(A_log[d * D_STATE + n]);
    const float Dv = Dp[d];

    float h[D_STATE];
    size_t base = (size_t)(b * PCH + p) * D_STATE * D_INNER + d;
    #pragma unroll
    for (int n = 0; n < D_STATE; n++) h[n] = hstart[base + (size_t)n * D_INNER];

    const float* dtp = dbl + ((size_t)b * SEQ + t0) * NCAT + d;
    const float* bp  = dbl + ((size_t)b * SEQ + t0) * NCAT + 1024;
    const size_t off0 = ((size_t)b * SEQ + t0) * D_INNER + d;
    const float* up = ubuf + off0;
    const float* zp = zbuf + off0;
    ushort_t* yp    = yout + off0;

    for (int t = 0; t < CLEN; t++) {
        float dtv = dtp[(size_t)t * NCAT];
        float uv  = up[(size_t)t * D_INNER];
        float zv  = zp[(size_t)t * D_INNER];
        float dtu = dtv * uv;
        float y = 0.f;
        #pragma unroll
        for (int n = 0; n < D_STATE; n++) {
            h[n] = fmaf(__expf(dtv * A[n]), h[n], dtu * bp[t * NCAT + n]);
            y = fmaf(h[n], bp[t * NCAT + 16 + n], y);
        }
        float res = fmaf(uv, Dv, y);
        res *= zv / (1.f + __expf(-zv));
        yp[(size_t)t * D_INNER] = f2bf(res);
    }
}

// ---------------------------------------------------------------------------
__global__ __launch_bounds__(256) void softmax_kernel(
    const float* __restrict__ in, float* __restrict__ out)
{
    const int idx = blockIdx.x * 256 + threadIdx.x;
    float v = in[idx];
    float m = v;
    #pragma unroll
    for (int off = 16; off > 0; off >>= 1) m = fmaxf(m, __shfl_xor(m, off, 32));
    float e = expf(v - m);
    float s = e;
    #pragma unroll
    for (int off = 16; off > 0; off >>= 1) s += __shfl_xor(s, off, 32);
    out[idx] = e / s;
}

// ---------------------------------------------------------------------------
extern "C" void kernel_launch(void* const* d_in, const int* in_sizes, int n_in,
                              void* d_out, int out_size, void* d_ws, size_t ws_size,
                              hipStream_t stream)
{
    const float* x       = (const float*)d_in[0];
    const float* lin1_w  = (const float*)d_in[1];
    const float* lin1_b  = (const float*)d_in[2];
    const float* norm_w  = (const float*)d_in[3];
    const float* in_w    = (const float*)d_in[4];
    const float* conv_w  = (const float*)d_in[5];
    const float* conv_b  = (const float*)d_in[6];
    const float* xproj_w = (const float*)d_in[7];
    const float* dt_w    = (const float*)d_in[8];
    const float* dt_b    = (const float*)d_in[9];
    const float* A_log   = (const float*)d_in[10];
    const float* Dp      = (const float*)d_in[11];
    const float* out_w   = (const float*)d_in[12];
    const float* lin2_w  = (const float*)d_in[13];
    const float* lin2_b  = (const float*)d_in[14];
    float* outp = (float*)d_out;
    (void)ws_size; (void)in_sizes; (void)n_in; (void)out_size;

    float* ws = (float*)d_ws;
    const size_t F1M = 1u << 20;
    float* h     = ws;                   // 2M floats
    float* xp    = h + 2 * F1M;          // 4M (conv in; hfin alias after)
    float* z     = xp + 4 * F1M;         // 4M
    float* xc    = z + 4 * F1M;          // 4M (fp32 u)
    float* dbl   = xc + 4 * F1M;         // 4096*1152 = 4.5M
    float* sumdt = dbl + (size_t)NTOK * NCAT;              // 128K
    ushort_t* hn_bf = (ushort_t*)(sumdt + BATCH * PCH * D_INNER); // 1M fl
    ushort_t* xb    = (ushort_t*)((float*)hn_bf + 1 * F1M);       // 2M fl
    ushort_t* wt    = (ushort_t*)((float*)xb + 2 * F1M);
    ushort_t* lin1_wt = wt;                                   // 512*1024
    ushort_t* in_wt   = lin1_wt + (size_t)512 * 1024;         // 4*2048*512
    ushort_t* out_wt  = in_wt + (size_t)4 * 2048 * 512;       // 4*512*1024
    ushort_t* lin2_wt = out_wt + (size_t)4 * 512 * 1024;      // 1024*512
    ushort_t* wcat    = lin2_wt + (size_t)1024 * 512;         // 4*1152*1024
    float* hfin = xp;

    dim3 blk(256);

    // --- weight prep ---
    transpose_cast_kernel<<<dim3(512 / 32, 1024 / 32), blk, 0, stream>>>(
        lin1_w, lin1_wt, LATENT, D_MODEL);
    for (int l = 0; l < N_LAYERS; l++) {
        transpose_cast_kernel<<<dim3(2048 / 32, 512 / 32), blk, 0, stream>>>(
            in_w + (size_t)l * 512 * 2048, in_wt + (size_t)l * 2048 * 512, 512, 2048);
        transpose_cast_kernel<<<dim3(512 / 32, 1024 / 32), blk, 0, stream>>>(
            out_w + (size_t)l * 1024 * 512, out_wt + (size_t)l * 512 * 1024, 1024, 512);
    }
    transpose_cast_kernel<<<dim3(1024 / 32, 512 / 32), blk, 0, stream>>>(
        lin2_w, lin2_wt, D_MODEL, LATENT);
    build_wcat_kernel<<<dim3(NCAT, N_LAYERS), blk, 0, stream>>>(
        xproj_w, dt_w, wcat);

    // x -> bf16
    cast_bf16_kernel<<<dim3((NTOK * LATENT) / 256), blk, 0, stream>>>(x, xb);

    // lin1: h = x_bf @ lin1_wt^T + b
    gemm_bf16_kernel<<<dim3(D_MODEL / 128, NTOK / 128), blk, 0, stream>>>(
        xb, LATENT, lin1_wt, LATENT, h, D_MODEL, lin1_b,
        NTOK, D_MODEL, LATENT, 1);

    for (int l = 0; l < N_LAYERS; l++) {
        const float* nw = norm_w + (size_t)l * D_MODEL;
        const float* cw = conv_w + (size_t)l * D_INNER * KCONV;
        const float* cb = conv_b + (size_t)l * D_INNER;
        const float* db = dt_b + (size_t)l * D_INNER;
        const float* al = A_log + (size_t)l * D_INNER * D_STATE;
        const float* dp = Dp + (size_t)l * D_INNER;
        const ushort_t* iwt = in_wt + (size_t)l * 2048 * 512;
        const ushort_t* owt = out_wt + (size_t)l * 512 * 1024;
        const ushort_t* wc  = wcat + (size_t)l * NCAT * D_INNER;

        rmsnorm_kernel<<<dim3(NTOK), blk, 0, stream>>>(h, nw, hn_bf);

        // in-proj split: xp = hn@W[:, :1024], z = hn@W[:, 1024:]
        gemm_bf16_kernel<<<dim3(D_INNER / 128, NTOK / 128), blk, 0, stream>>>(
            hn_bf, D_MODEL, iwt, D_MODEL, xp, D_INNER, nullptr,
            NTOK, D_INNER, D_MODEL, 0);
        gemm_bf16_kernel<<<dim3(D_INNER / 128, NTOK / 128), blk, 0, stream>>>(
            hn_bf, D_MODEL, iwt + (size_t)1024 * 512, D_MODEL, z, D_INNER, nullptr,
            NTOK, D_INNER, D_MODEL, 0);

        // conv + silu: xp -> xc (fp32) + xb (bf16)
        conv_silu_kernel<<<dim3((NTOK * D_INNER) / 256), blk, 0, stream>>>(
            xp, cw, cb, xc, xb);

        // merged xproj+dt GEMM: dbl[:, :1024]=softplus(xc@Wdt+dt_b),
        //                       dbl[:, 1024:1056]=B|C
        gemm_bf16_kernel<<<dim3(NCAT / 128, NTOK / 128), blk, 0, stream>>>(
            xb, D_INNER, wc, D_INNER, dbl, NCAT, db,
            NTOK, NCAT, D_INNER, 4);

        // chunked scan (hfin aliases xp, dead after conv)
        scan_pass1<<<dim3(BATCH * PCH * (D_INNER / 256)), blk, 0, stream>>>(
            dbl, xc, al, hfin, sumdt);
        scan_pass2<<<dim3(BATCH * D_STATE * (D_INNER / 256)), blk, 0, stream>>>(
            al, sumdt, hfin);
        scan_pass3<<<dim3(BATCH * PCH * (D_INNER / 256)), blk, 0, stream>>>(
            dbl, z, al, dp, hfin, xc, xb);

        // h += y_bf @ out_wt^T
        gemm_bf16_kernel<<<dim3(D_MODEL / 128, NTOK / 128), blk, 0, stream>>>(
            xb, D_INNER, owt, D_INNER, h, D_MODEL, nullptr,
            NTOK, D_MODEL, D_INNER, 2);
    }

    // h -> bf16, lin2, softmax
    cast_bf16_kernel<<<dim3((NTOK * D_MODEL) / 256), blk, 0, stream>>>(h, xb);
    gemm_bf16_kernel<<<dim3(LATENT / 128, NTOK / 128), blk, 0, stream>>>(
        xb, D_MODEL, lin2_wt, D_MODEL, xp, LATENT, lin2_b,
        NTOK, LATENT, D_MODEL, 1);
    softmax_kernel<<<dim3((NTOK * LATENT) / 256), blk, 0, stream>>>(xp, outp);
}

// Round 6
// 1033.479 us; speedup vs baseline: 4.3989x; 1.0536x over previous
//
#include <hip/hip_runtime.h>
#include <math.h>

#define D_MODEL 512
#define N_LAYERS 4
#define LATENT 1024
#define D_INNER 1024
#define D_STATE 16
#define DT_RANK 32
#define KCONV 4
#define BATCH 4
#define SEQ 1024
#define NTOK (BATCH * SEQ) /* 4096 */
#define PCH 32
#define CLEN 32
#define NCAT 1152  /* merged xproj+dt GEMM N: 1024 dt | 32 B/C | 96 pad */

typedef __attribute__((ext_vector_type(8))) short short8;
typedef __attribute__((ext_vector_type(4))) float floatx4;
typedef unsigned short ushort_t;

__device__ __forceinline__ ushort_t f2bf(float f) {
    union { float f; unsigned u; } v; v.f = f;
    unsigned r = v.u + 0x7FFFu + ((v.u >> 16) & 1u);  // RNE
    return (ushort_t)(r >> 16);
}

// ---------------------------------------------------------------------------
// bf16 MFMA GEMM: C[M,N] = A[M,K](bf16) @ Bt[N,K](bf16)^T (+bias)(+C)
// flags: 1 = add bias[n], 2 = accumulate into C,
//        4 = merged-dt epilogue: for n<1024 only, v = softplus(v + bias[n]).
// BM=BN=128, BK=32, 256 threads (4 waves), each wave 64x64 via 4x4 MFMAs.
// ---------------------------------------------------------------------------
__global__ __launch_bounds__(256) void gemm_bf16_kernel(
    const ushort_t* __restrict__ A, int lda,
    const ushort_t* __restrict__ Bt, int ldb,
    float* __restrict__ C, int ldc,
    const float* __restrict__ bias,
    int M, int N, int K, int flags)
{
    __shared__ ushort_t As[128][40];
    __shared__ ushort_t Bs[128][40];
    const int tid = threadIdx.x;
    const int m0 = blockIdx.y * 128;
    const int n0 = blockIdx.x * 128;
    const int w = tid >> 6;
    const int lane = tid & 63;
    const int quad = lane >> 4;
    const int l16 = lane & 15;
    const int wm = (w & 1) * 64;
    const int wn = (w >> 1) * 64;

    const int r = tid >> 2;
    const int c = (tid & 3) << 3;

    floatx4 acc[4][4] = {};

    for (int k0 = 0; k0 < K; k0 += 32) {
        __syncthreads();
        *(uint4*)&As[r][c]      = *(const uint4*)&A[(size_t)(m0 + r) * lda + k0 + c];
        *(uint4*)&As[r + 64][c] = *(const uint4*)&A[(size_t)(m0 + r + 64) * lda + k0 + c];
        *(uint4*)&Bs[r][c]      = *(const uint4*)&Bt[(size_t)(n0 + r) * ldb + k0 + c];
        *(uint4*)&Bs[r + 64][c] = *(const uint4*)&Bt[(size_t)(n0 + r + 64) * ldb + k0 + c];
        __syncthreads();

        short8 af[4], bfr[4];
        #pragma unroll
        for (int i = 0; i < 4; i++)
            af[i] = *(const short8*)&As[wm + i * 16 + l16][quad * 8];
        #pragma unroll
        for (int j = 0; j < 4; j++)
            bfr[j] = *(const short8*)&Bs[wn + j * 16 + l16][quad * 8];
        #pragma unroll
        for (int i = 0; i < 4; i++)
            #pragma unroll
            for (int j = 0; j < 4; j++)
                acc[i][j] = __builtin_amdgcn_mfma_f32_16x16x32_bf16(
                    af[i], bfr[j], acc[i][j], 0, 0, 0);
    }

    // C/D layout (m89-verified): col = lane&15, row = quad*4 + reg.
    #pragma unroll
    for (int j = 0; j < 4; j++) {
        int n = n0 + wn + j * 16 + l16;
        float bv = (flags & 1) ? bias[n] : 0.f;
        bool do_sp = (flags & 4) && (n < 1024);
        float spb = do_sp ? bias[n] : 0.f;
        #pragma unroll
        for (int i = 0; i < 4; i++) {
            int mrow = m0 + wm + i * 16 + quad * 4;
            #pragma unroll
            for (int rr = 0; rr < 4; rr++) {
                size_t idx = (size_t)(mrow + rr) * ldc + n;
                float v = acc[i][j][rr] + bv;
                if (do_sp) {
                    v += spb;
                    v = (v > 20.f) ? v : log1pf(__expf(v));
                }
                if (flags & 2) v += C[idx];
                C[idx] = v;
            }
        }
    }
}

// ---------------------------------------------------------------------------
// build_wdt: Wcat rows 0..1023 = (xw[:, :32] @ dt_w)^T, bf16 [n][k].
// Proper LDS-tiled GEMM: out[n][k] = sum_r xw[k][r]*dtw[r][n].
// 64x64 tile per block, grid (16 n-tiles, 16 k-tiles, N_LAYERS).
// ---------------------------------------------------------------------------
__global__ __launch_bounds__(256) void build_wdt_kernel(
    const float* __restrict__ xproj_w, const float* __restrict__ dt_w,
    ushort_t* __restrict__ wcat)
{
    const int l = blockIdx.z;
    const int n0 = blockIdx.x * 64;
    const int k0 = blockIdx.y * 64;
    const float* xw  = xproj_w + (size_t)l * D_INNER * 64;
    const float* dtw = dt_w + (size_t)l * DT_RANK * D_INNER;

    __shared__ float xs[64][33];   // [k][r]
    __shared__ float ds[32][65];   // [r][n]

    const int tid = threadIdx.x;
    {   // xw tile: 64 k-rows x 32 r-cols
        int row = tid >> 2;
        int col = (tid & 3) * 8;
        #pragma unroll
        for (int q = 0; q < 8; q++)
            xs[row][col + q] = xw[(size_t)(k0 + row) * 64 + col + q];
    }
    {   // dtw tile: 32 r-rows x 64 n-cols
        int row = tid >> 3;
        int col = (tid & 7) * 8;
        #pragma unroll
        for (int q = 0; q < 8; q++)
            ds[row][col + q] = dtw[(size_t)row * D_INNER + n0 + col + q];
    }
    __syncthreads();

    const int ty = tid & 15;   // k quad (fast dim -> coalesced writes)
    const int tx = tid >> 4;   // n quad
    float acc[4][4] = {};      // [j:n][i:k]
    #pragma unroll
    for (int r = 0; r < 32; r++) {
        float a[4], b[4];
        #pragma unroll
        for (int i = 0; i < 4; i++) a[i] = xs[ty * 4 + i][r];
        #pragma unroll
        for (int j = 0; j < 4; j++) b[j] = ds[r][tx * 4 + j];
        #pragma unroll
        for (int j = 0; j < 4; j++)
            #pragma unroll
            for (int i = 0; i < 4; i++)
                acc[j][i] = fmaf(a[i], b[j], acc[j][i]);
    }
    #pragma unroll
    for (int j = 0; j < 4; j++) {
        int n = n0 + tx * 4 + j;
        ushort4 o;
        o.x = f2bf(acc[j][0]); o.y = f2bf(acc[j][1]);
        o.z = f2bf(acc[j][2]); o.w = f2bf(acc[j][3]);
        *(ushort4*)&wcat[((size_t)l * NCAT + n) * D_INNER + k0 + ty * 4] = o;
    }
}

// ---------------------------------------------------------------------------
// build_wbc: Wcat rows 1024..1151: j<32 -> xw[k][32+j] cast; else zero pad.
// (Pad MUST be written every launch: d_ws is re-poisoned to 0xAA.)
// ---------------------------------------------------------------------------
__global__ __launch_bounds__(256) void build_wbc_kernel(
    const float* __restrict__ xproj_w, ushort_t* __restrict__ wcat)
{
    const int idx = blockIdx.x * 256 + threadIdx.x;  // over L*128*1024
    const int k = idx & 1023;
    const int j = (idx >> 10) & 127;
    const int l = idx >> 17;
    ushort_t v = 0;
    if (j < 32)
        v = f2bf(xproj_w[((size_t)l * D_INNER + k) * 64 + 32 + j]);
    wcat[((size_t)l * NCAT + 1024 + j) * D_INNER + k] = v;
}

// ---------------------------------------------------------------------------
// Transpose-cast: fp32 [K][N] -> bf16 [N][K]. 32x32 tiles, 256 threads.
// ---------------------------------------------------------------------------
__global__ __launch_bounds__(256) void transpose_cast_kernel(
    const float* __restrict__ in, ushort_t* __restrict__ out, int K, int N)
{
    __shared__ float tile[32][33];
    const int n0 = blockIdx.x * 32, k0 = blockIdx.y * 32;
    const int tx = threadIdx.x & 31, ty = threadIdx.x >> 5;
    #pragma unroll
    for (int i = 0; i < 4; i++)
        tile[ty + i * 8][tx] = in[(size_t)(k0 + ty + i * 8) * N + n0 + tx];
    __syncthreads();
    #pragma unroll
    for (int i = 0; i < 4; i++)
        out[(size_t)(n0 + ty + i * 8) * K + k0 + tx] = f2bf(tile[tx][ty + i * 8]);
}

// ---------------------------------------------------------------------------
__global__ __launch_bounds__(256) void cast_bf16_kernel(
    const float* __restrict__ in, ushort_t* __restrict__ out)
{
    const int i = blockIdx.x * 256 + threadIdx.x;
    out[i] = f2bf(in[i]);
}

// ---------------------------------------------------------------------------
// RMSNorm over rows of D_MODEL=512, bf16 output. One block per row.
// ---------------------------------------------------------------------------
__global__ __launch_bounds__(256) void rmsnorm_kernel(
    const float* __restrict__ x, const float* __restrict__ w,
    ushort_t* __restrict__ y)
{
    const int row = blockIdx.x;
    const float* xr = x + (size_t)row * D_MODEL;
    ushort_t* yr = y + (size_t)row * D_MODEL;
    const int tid = threadIdx.x;

    float v0 = xr[tid], v1 = xr[tid + 256];
    float ss = v0 * v0 + v1 * v1;
    #pragma unroll
    for (int off = 32; off > 0; off >>= 1) ss += __shfl_down(ss, off);

    __shared__ float wsum[4];
    __shared__ float scale_s;
    int wid = tid >> 6, lane = tid & 63;
    if (lane == 0) wsum[wid] = ss;
    __syncthreads();
    if (tid == 0) {
        float tot = wsum[0] + wsum[1] + wsum[2] + wsum[3];
        scale_s = 1.0f / sqrtf(tot / (float)D_MODEL + 1e-5f);
    }
    __syncthreads();
    float sc = scale_s;
    yr[tid] = f2bf(v0 * sc * w[tid]);
    yr[tid + 256] = f2bf(v1 * sc * w[tid + 256]);
}

// ---------------------------------------------------------------------------
// Causal dwconv (K=4) + bias + silu. Dual output: fp32 (for scan u) and
// bf16 (A-operand of the merged xproj/dt GEMM).
// ---------------------------------------------------------------------------
__global__ __launch_bounds__(256) void conv_silu_kernel(
    const float* __restrict__ xp, const float* __restrict__ w,
    const float* __restrict__ bconv, float* __restrict__ out,
    ushort_t* __restrict__ outb)
{
    const int idx = blockIdx.x * 256 + threadIdx.x;
    const int d = idx & (D_INNER - 1);
    const int t = (idx >> 10) & (SEQ - 1);

    float s = 0.f;
    #pragma unroll
    for (int k = 0; k < KCONV; k++) {
        int tt = t + k - (KCONV - 1);
        if (tt >= 0) s = fmaf(xp[idx + (k - (KCONV - 1)) * D_INNER], w[d * KCONV + k], s);
    }
    s += bconv[d];
    float r = s / (1.f + __expf(-s));
    out[idx] = r;
    outb[idx] = f2bf(r);
}

// ---------------------------------------------------------------------------
// Chunked selective scan (3 passes), CLEN=32.
// dt and B/C live in the merged dbl buffer, row stride NCAT:
//   dbl[row][d]        = dt (d<1024, already softplus'ed)
//   dbl[row][1024+n]   = B[n],  dbl[row][1040+n] = C[n]
// ---------------------------------------------------------------------------
__global__ __launch_bounds__(256) void scan_pass1(
    const float* __restrict__ dbl, const float* __restrict__ ubuf,
    const float* __restrict__ A_log,
    float* __restrict__ hfin, float* __restrict__ sumdt)
{
    const int tid = threadIdx.x;
    const int b = blockIdx.x >> 7;
    const int p = (blockIdx.x >> 2) & 31;
    const int d = ((blockIdx.x & 3) << 8) + tid;
    const int t0 = p * CLEN;

    float A[D_STATE];
    #pragma unroll
    for (int n = 0; n < D_STATE; n++) A[n] = -expf(A_log[d * D_STATE + n]);

    float h[D_STATE] = {};
    float sdt = 0.f;

    const float* dtp = dbl + ((size_t)b * SEQ + t0) * NCAT + d;
    const float* bp  = dbl + ((size_t)b * SEQ + t0) * NCAT + 1024;
    const float* up  = ubuf + ((size_t)b * SEQ + t0) * D_INNER + d;

    for (int t = 0; t < CLEN; t++) {
        float dtv = dtp[(size_t)t * NCAT];
        float uv  = up[(size_t)t * D_INNER];
        float dtu = dtv * uv;
        sdt += dtv;
        #pragma unroll
        for (int n = 0; n < D_STATE; n++)
            h[n] = fmaf(__expf(dtv * A[n]), h[n], dtu * bp[t * NCAT + n]);
    }

    size_t base = (size_t)(b * PCH + p) * D_STATE * D_INNER + d;
    #pragma unroll
    for (int n = 0; n < D_STATE; n++) hfin[base + (size_t)n * D_INNER] = h[n];
    sumdt[(size_t)(b * PCH + p) * D_INNER + d] = sdt;
}

__global__ __launch_bounds__(256) void scan_pass2(
    const float* __restrict__ A_log, const float* __restrict__ sumdt,
    float* __restrict__ hc)
{
    const int tid = threadIdx.x;
    const int b = blockIdx.x >> 6;
    const int n = (blockIdx.x >> 2) & 15;
    const int d = ((blockIdx.x & 3) << 8) + tid;

    const float Aval = -expf(A_log[d * D_STATE + n]);
    float h = 0.f;
    for (int p = 0; p < PCH; p++) {
        size_t idx = ((size_t)(b * PCH + p) * D_STATE + n) * D_INNER + d;
        float fin = hc[idx];
        hc[idx] = h;
        h = fmaf(__expf(Aval * sumdt[(size_t)(b * PCH + p) * D_INNER + d]), h, fin);
    }
}

__global__ __launch_bounds__(256) void scan_pass3(
    const float* __restrict__ dbl, const float* __restrict__ zbuf,
    const float* __restrict__ A_log, const float* __restrict__ Dp,
    const float* __restrict__ hstart, const float* __restrict__ ubuf,
    ushort_t* __restrict__ yout)
{
    const int tid = threadIdx.x;
    const int b = blockIdx.x >> 7;
    const int p = (blockIdx.x >> 2) & 31;
    const int d = ((blockIdx.x & 3) << 8) + tid;
    const int t0 = p * CLEN;

    float A[D_STATE];
    #pragma unroll
    for (int n = 0; n < D_STATE; n++) A[n] = -expf(A_log[d * D_STATE + n]);
    const float Dv = Dp[d];

    float h[D_STATE];
    size_t base = (size_t)(b * PCH + p) * D_STATE * D_INNER + d;
    #pragma unroll
    for (int n = 0; n < D_STATE; n++) h[n] = hstart[base + (size_t)n * D_INNER];

    const float* dtp = dbl + ((size_t)b * SEQ + t0) * NCAT + d;
    const float* bp  = dbl + ((size_t)b * SEQ + t0) * NCAT + 1024;
    const size_t off0 = ((size_t)b * SEQ + t0) * D_INNER + d;
    const float* up = ubuf + off0;
    const float* zp = zbuf + off0;
    ushort_t* yp    = yout + off0;

    for (int t = 0; t < CLEN; t++) {
        float dtv = dtp[(size_t)t * NCAT];
        float uv  = up[(size_t)t * D_INNER];
        float zv  = zp[(size_t)t * D_INNER];
        float dtu = dtv * uv;
        float y = 0.f;
        #pragma unroll
        for (int n = 0; n < D_STATE; n++) {
            h[n] = fmaf(__expf(dtv * A[n]), h[n], dtu * bp[t * NCAT + n]);
            y = fmaf(h[n], bp[t * NCAT + 16 + n], y);
        }
        float res = fmaf(uv, Dv, y);
        res *= zv / (1.f + __expf(-zv));
        yp[(size_t)t * D_INNER] = f2bf(res);
    }
}

// ---------------------------------------------------------------------------
__global__ __launch_bounds__(256) void softmax_kernel(
    const float* __restrict__ in, float* __restrict__ out)
{
    const int idx = blockIdx.x * 256 + threadIdx.x;
    float v = in[idx];
    float m = v;
    #pragma unroll
    for (int off = 16; off > 0; off >>= 1) m = fmaxf(m, __shfl_xor(m, off, 32));
    float e = expf(v - m);
    float s = e;
    #pragma unroll
    for (int off = 16; off > 0; off >>= 1) s += __shfl_xor(s, off, 32);
    out[idx] = e / s;
}

// ---------------------------------------------------------------------------
extern "C" void kernel_launch(void* const* d_in, const int* in_sizes, int n_in,
                              void* d_out, int out_size, void* d_ws, size_t ws_size,
                              hipStream_t stream)
{
    const float* x       = (const float*)d_in[0];
    const float* lin1_w  = (const float*)d_in[1];
    const float* lin1_b  = (const float*)d_in[2];
    const float* norm_w  = (const float*)d_in[3];
    const float* in_w    = (const float*)d_in[4];
    const float* conv_w  = (const float*)d_in[5];
    const float* conv_b  = (const float*)d_in[6];
    const float* xproj_w = (const float*)d_in[7];
    const float* dt_w    = (const float*)d_in[8];
    const float* dt_b    = (const float*)d_in[9];
    const float* A_log   = (const float*)d_in[10];
    const float* Dp      = (const float*)d_in[11];
    const float* out_w   = (const float*)d_in[12];
    const float* lin2_w  = (const float*)d_in[13];
    const float* lin2_b  = (const float*)d_in[14];
    float* outp = (float*)d_out;
    (void)ws_size; (void)in_sizes; (void)n_in; (void)out_size;

    float* ws = (float*)d_ws;
    const size_t F1M = 1u << 20;
    float* h     = ws;                   // 2M floats
    float* xp    = h + 2 * F1M;          // 4M (conv in; hfin alias after)
    float* z     = xp + 4 * F1M;         // 4M
    float* xc    = z + 4 * F1M;          // 4M (fp32 u)
    float* dbl   = xc + 4 * F1M;         // 4096*1152 = 4.5M
    float* sumdt = dbl + (size_t)NTOK * NCAT;              // 128K
    ushort_t* hn_bf = (ushort_t*)(sumdt + BATCH * PCH * D_INNER); // 1M fl
    ushort_t* xb    = (ushort_t*)((float*)hn_bf + 1 * F1M);       // 2M fl
    ushort_t* wt    = (ushort_t*)((float*)xb + 2 * F1M);
    ushort_t* lin1_wt = wt;                                   // 512*1024
    ushort_t* in_wt   = lin1_wt + (size_t)512 * 1024;         // 4*2048*512
    ushort_t* out_wt  = in_wt + (size_t)4 * 2048 * 512;       // 4*512*1024
    ushort_t* lin2_wt = out_wt + (size_t)4 * 512 * 1024;      // 1024*512
    ushort_t* wcat    = lin2_wt + (size_t)1024 * 512;         // 4*1152*1024
    float* hfin = xp;

    dim3 blk(256);

    // --- weight prep ---
    transpose_cast_kernel<<<dim3(512 / 32, 1024 / 32), blk, 0, stream>>>(
        lin1_w, lin1_wt, LATENT, D_MODEL);
    for (int l = 0; l < N_LAYERS; l++) {
        transpose_cast_kernel<<<dim3(2048 / 32, 512 / 32), blk, 0, stream>>>(
            in_w + (size_t)l * 512 * 2048, in_wt + (size_t)l * 2048 * 512, 512, 2048);
        transpose_cast_kernel<<<dim3(512 / 32, 1024 / 32), blk, 0, stream>>>(
            out_w + (size_t)l * 1024 * 512, out_wt + (size_t)l * 512 * 1024, 1024, 512);
    }
    transpose_cast_kernel<<<dim3(1024 / 32, 512 / 32), blk, 0, stream>>>(
        lin2_w, lin2_wt, D_MODEL, LATENT);
    build_wdt_kernel<<<dim3(16, 16, N_LAYERS), blk, 0, stream>>>(
        xproj_w, dt_w, wcat);
    build_wbc_kernel<<<dim3((N_LAYERS * 128 * 1024) / 256), blk, 0, stream>>>(
        xproj_w, wcat);

    // x -> bf16
    cast_bf16_kernel<<<dim3((NTOK * LATENT) / 256), blk, 0, stream>>>(x, xb);

    // lin1: h = x_bf @ lin1_wt^T + b
    gemm_bf16_kernel<<<dim3(D_MODEL / 128, NTOK / 128), blk, 0, stream>>>(
        xb, LATENT, lin1_wt, LATENT, h, D_MODEL, lin1_b,
        NTOK, D_MODEL, LATENT, 1);

    for (int l = 0; l < N_LAYERS; l++) {
        const float* nw = norm_w + (size_t)l * D_MODEL;
        const float* cw = conv_w + (size_t)l * D_INNER * KCONV;
        const float* cb = conv_b + (size_t)l * D_INNER;
        const float* db = dt_b + (size_t)l * D_INNER;
        const float* al = A_log + (size_t)l * D_INNER * D_STATE;
        const float* dp = Dp + (size_t)l * D_INNER;
        const ushort_t* iwt = in_wt + (size_t)l * 2048 * 512;
        const ushort_t* owt = out_wt + (size_t)l * 512 * 1024;
        const ushort_t* wc  = wcat + (size_t)l * NCAT * D_INNER;

        rmsnorm_kernel<<<dim3(NTOK), blk, 0, stream>>>(h, nw, hn_bf);

        // in-proj split: xp = hn@W[:, :1024], z = hn@W[:, 1024:]
        gemm_bf16_kernel<<<dim3(D_INNER / 128, NTOK / 128), blk, 0, stream>>>(
            hn_bf, D_MODEL, iwt, D_MODEL, xp, D_INNER, nullptr,
            NTOK, D_INNER, D_MODEL, 0);
        gemm_bf16_kernel<<<dim3(D_INNER / 128, NTOK / 128), blk, 0, stream>>>(
            hn_bf, D_MODEL, iwt + (size_t)1024 * 512, D_MODEL, z, D_INNER, nullptr,
            NTOK, D_INNER, D_MODEL, 0);

        // conv + silu: xp -> xc (fp32) + xb (bf16)
        conv_silu_kernel<<<dim3((NTOK * D_INNER) / 256), blk, 0, stream>>>(
            xp, cw, cb, xc, xb);

        // merged xproj+dt GEMM: dbl[:, :1024]=softplus(xc@Wdt+dt_b),
        //                       dbl[:, 1024:1056]=B|C
        gemm_bf16_kernel<<<dim3(NCAT / 128, NTOK / 128), blk, 0, stream>>>(
            xb, D_INNER, wc, D_INNER, dbl, NCAT, db,
            NTOK, NCAT, D_INNER, 4);

        // chunked scan (hfin aliases xp, dead after conv)
        scan_pass1<<<dim3(BATCH * PCH * (D_INNER / 256)), blk, 0, stream>>>(
            dbl, xc, al, hfin, sumdt);
        scan_pass2<<<dim3(BATCH * D_STATE * (D_INNER / 256)), blk, 0, stream>>>(
            al, sumdt, hfin);
        scan_pass3<<<dim3(BATCH * PCH * (D_INNER / 256)), blk, 0, stream>>>(
            dbl, z, al, dp, hfin, xc, xb);

        // h += y_bf @ out_wt^T
        gemm_bf16_kernel<<<dim3(D_MODEL / 128, NTOK / 128), blk, 0, stream>>>(
            xb, D_INNER, owt, D_INNER, h, D_MODEL, nullptr,
            NTOK, D_MODEL, D_INNER, 2);
    }

    // h -> bf16, lin2, softmax
    cast_bf16_kernel<<<dim3((NTOK * D_MODEL) / 256), blk, 0, stream>>>(h, xb);
    gemm_bf16_kernel<<<dim3(LATENT / 128, NTOK / 128), blk, 0, stream>>>(
        xb, D_MODEL, lin2_wt, D_MODEL, xp, LATENT, lin2_b,
        NTOK, LATENT, D_MODEL, 1);
    softmax_kernel<<<dim3((NTOK * LATENT) / 256), blk, 0, stream>>>(xp, outp);
}

// Round 7
// 943.298 us; speedup vs baseline: 4.8194x; 1.0956x over previous
//
#include <hip/hip_runtime.h>
#include <math.h>

#define D_MODEL 512
#define N_LAYERS 4
#define LATENT 1024
#define D_INNER 1024
#define D_STATE 16
#define DT_RANK 32
#define KCONV 4
#define BATCH 4
#define SEQ 1024
#define NTOK (BATCH * SEQ) /* 4096 */
#define PCH 32
#define CLEN 32
#define NCAT 1152  /* merged xproj+dt GEMM N: 1024 dt | 32 B/C | 96 pad */

typedef __attribute__((ext_vector_type(8))) short short8;
typedef __attribute__((ext_vector_type(4))) float floatx4;
typedef unsigned short ushort_t;

__device__ __forceinline__ ushort_t f2bf(float f) {
    union { float f; unsigned u; } v; v.f = f;
    unsigned r = v.u + 0x7FFFu + ((v.u >> 16) & 1u);  // RNE
    return (ushort_t)(r >> 16);
}
__device__ __forceinline__ float bf2f(ushort_t u) {
    union { unsigned u; float f; } v; v.u = ((unsigned)u) << 16;
    return v.f;
}
// async global -> LDS, 16B per lane (verified width=16 on gfx950, m97).
__device__ __forceinline__ void gll16(const void* g, void* l) {
    __builtin_amdgcn_global_load_lds(
        (const __attribute__((address_space(1))) void*)g,
        (__attribute__((address_space(3))) void*)l, 16, 0, 0);
}

// ---------------------------------------------------------------------------
// bf16 MFMA GEMM: C[M,N] = A[M,K](bf16) @ Bt[N,K](bf16)^T (+bias)(+C)
// flags: 1 = add bias[n], 2 = accumulate into C,
//        4 = merged-dt epilogue: for n<1024 only, v = softplus(v + bias[n]).
// BM=BN=128, BK=32, 256 threads (4 waves), wave = 64x64 via 4x4 MFMAs.
// Staging: global_load_lds 16B/lane into UNPADDED [128][32] LDS (lane-order
// contiguous, required by the DMA), double-buffered; one-tile-ahead prefetch
// issued after the barrier so its latency overlaps the compute phase.
// ---------------------------------------------------------------------------
__global__ __launch_bounds__(256) void gemm_bf16_kernel(
    const ushort_t* __restrict__ A, int lda,
    const ushort_t* __restrict__ Bt, int ldb,
    float* __restrict__ C, int ldc,
    const float* __restrict__ bias,
    int M, int N, int K, int flags)
{
    __shared__ ushort_t As[2][128 * 32];
    __shared__ ushort_t Bs[2][128 * 32];
    const int tid = threadIdx.x;
    const int m0 = blockIdx.y * 128;
    const int n0 = blockIdx.x * 128;
    const int w = tid >> 6;
    const int lane = tid & 63;
    const int quad = lane >> 4;
    const int l16 = lane & 15;
    const int wm = (w & 1) * 64;
    const int wn = (w >> 1) * 64;

    // staging source: thread tid covers row (tid>>2), cols (tid&3)*8..+7
    const ushort_t* ga = A + (size_t)(m0 + (tid >> 2)) * lda + (tid & 3) * 8;
    const ushort_t* gb = Bt + (size_t)(n0 + (tid >> 2)) * ldb + (tid & 3) * 8;
    const size_t a64 = (size_t)64 * lda, b64 = (size_t)64 * ldb;
    const int lofs = tid * 8;  // LDS element offset (16B/lane, wave-contiguous)

    floatx4 acc[4][4] = {};
    const int nt = K >> 5;

    // prefetch tile 0 -> buf 0
    gll16(ga, &As[0][lofs]);
    gll16(ga + a64, &As[0][2048 + lofs]);
    gll16(gb, &Bs[0][lofs]);
    gll16(gb + b64, &Bs[0][2048 + lofs]);

    for (int kt = 0; kt < nt; kt++) {
        const int cur = kt & 1;
        // barrier drain (vmcnt(0)) completes tile-kt DMA (in flight during
        // the previous compute) and protects buf[1-cur] from overwrite.
        __syncthreads();
        if (kt + 1 < nt) {
            const ushort_t* pa = ga + (kt + 1) * 32;
            const ushort_t* pb = gb + (kt + 1) * 32;
            gll16(pa, &As[1 - cur][lofs]);
            gll16(pa + a64, &As[1 - cur][2048 + lofs]);
            gll16(pb, &Bs[1 - cur][lofs]);
            gll16(pb + b64, &Bs[1 - cur][2048 + lofs]);
        }
        short8 af[4], bfr[4];
        #pragma unroll
        for (int i = 0; i < 4; i++)
            af[i] = *(const short8*)&As[cur][(wm + i * 16 + l16) * 32 + quad * 8];
        #pragma unroll
        for (int j = 0; j < 4; j++)
            bfr[j] = *(const short8*)&Bs[cur][(wn + j * 16 + l16) * 32 + quad * 8];
        #pragma unroll
        for (int i = 0; i < 4; i++)
            #pragma unroll
            for (int j = 0; j < 4; j++)
                acc[i][j] = __builtin_amdgcn_mfma_f32_16x16x32_bf16(
                    af[i], bfr[j], acc[i][j], 0, 0, 0);
    }

    // C/D layout (m89-verified): col = lane&15, row = quad*4 + reg.
    #pragma unroll
    for (int j = 0; j < 4; j++) {
        int n = n0 + wn + j * 16 + l16;
        float bv = (flags & 1) ? bias[n] : 0.f;
        bool do_sp = (flags & 4) && (n < 1024);
        float spb = do_sp ? bias[n] : 0.f;
        #pragma unroll
        for (int i = 0; i < 4; i++) {
            int mrow = m0 + wm + i * 16 + quad * 4;
            #pragma unroll
            for (int rr = 0; rr < 4; rr++) {
                size_t idx = (size_t)(mrow + rr) * ldc + n;
                float v = acc[i][j][rr] + bv;
                if (do_sp) {
                    v += spb;
                    v = (v > 20.f) ? v : log1pf(__expf(v));
                }
                if (flags & 2) v += C[idx];
                C[idx] = v;
            }
        }
    }
}

// ---------------------------------------------------------------------------
// build_wdt: Wcat rows 0..1023 = (xw[:, :32] @ dt_w)^T, bf16 [n][k].
// ---------------------------------------------------------------------------
__global__ __launch_bounds__(256) void build_wdt_kernel(
    const float* __restrict__ xproj_w, const float* __restrict__ dt_w,
    ushort_t* __restrict__ wcat)
{
    const int l = blockIdx.z;
    const int n0 = blockIdx.x * 64;
    const int k0 = blockIdx.y * 64;
    const float* xw  = xproj_w + (size_t)l * D_INNER * 64;
    const float* dtw = dt_w + (size_t)l * DT_RANK * D_INNER;

    __shared__ float xs[64][33];   // [k][r]
    __shared__ float ds[32][65];   // [r][n]

    const int tid = threadIdx.x;
    {
        int row = tid >> 2;
        int col = (tid & 3) * 8;
        #pragma unroll
        for (int q = 0; q < 8; q++)
            xs[row][col + q] = xw[(size_t)(k0 + row) * 64 + col + q];
    }
    {
        int row = tid >> 3;
        int col = (tid & 7) * 8;
        #pragma unroll
        for (int q = 0; q < 8; q++)
            ds[row][col + q] = dtw[(size_t)row * D_INNER + n0 + col + q];
    }
    __syncthreads();

    const int ty = tid & 15;
    const int tx = tid >> 4;
    float acc[4][4] = {};
    #pragma unroll
    for (int r = 0; r < 32; r++) {
        float a[4], b[4];
        #pragma unroll
        for (int i = 0; i < 4; i++) a[i] = xs[ty * 4 + i][r];
        #pragma unroll
        for (int j = 0; j < 4; j++) b[j] = ds[r][tx * 4 + j];
        #pragma unroll
        for (int j = 0; j < 4; j++)
            #pragma unroll
            for (int i = 0; i < 4; i++)
                acc[j][i] = fmaf(a[i], b[j], acc[j][i]);
    }
    #pragma unroll
    for (int j = 0; j < 4; j++) {
        int n = n0 + tx * 4 + j;
        ushort4 o;
        o.x = f2bf(acc[j][0]); o.y = f2bf(acc[j][1]);
        o.z = f2bf(acc[j][2]); o.w = f2bf(acc[j][3]);
        *(ushort4*)&wcat[((size_t)l * NCAT + n) * D_INNER + k0 + ty * 4] = o;
    }
}

// ---------------------------------------------------------------------------
// build_wbc: Wcat rows 1024..1151: j<32 -> xw[k][32+j] cast; else zero pad.
// (Pad MUST be written every launch: d_ws is re-poisoned to 0xAA.)
// ---------------------------------------------------------------------------
__global__ __launch_bounds__(256) void build_wbc_kernel(
    const float* __restrict__ xproj_w, ushort_t* __restrict__ wcat)
{
    const int idx = blockIdx.x * 256 + threadIdx.x;
    const int k = idx & 1023;
    const int j = (idx >> 10) & 127;
    const int l = idx >> 17;
    ushort_t v = 0;
    if (j < 32)
        v = f2bf(xproj_w[((size_t)l * D_INNER + k) * 64 + 32 + j]);
    wcat[((size_t)l * NCAT + 1024 + j) * D_INNER + k] = v;
}

// ---------------------------------------------------------------------------
__global__ __launch_bounds__(256) void transpose_cast_kernel(
    const float* __restrict__ in, ushort_t* __restrict__ out, int K, int N)
{
    __shared__ float tile[32][33];
    const int n0 = blockIdx.x * 32, k0 = blockIdx.y * 32;
    const int tx = threadIdx.x & 31, ty = threadIdx.x >> 5;
    #pragma unroll
    for (int i = 0; i < 4; i++)
        tile[ty + i * 8][tx] = in[(size_t)(k0 + ty + i * 8) * N + n0 + tx];
    __syncthreads();
    #pragma unroll
    for (int i = 0; i < 4; i++)
        out[(size_t)(n0 + ty + i * 8) * K + k0 + tx] = f2bf(tile[tx][ty + i * 8]);
}

// ---------------------------------------------------------------------------
__global__ __launch_bounds__(256) void cast_bf16_kernel(
    const float* __restrict__ in, ushort_t* __restrict__ out)
{
    const int i = blockIdx.x * 256 + threadIdx.x;
    out[i] = f2bf(in[i]);
}

// ---------------------------------------------------------------------------
__global__ __launch_bounds__(256) void rmsnorm_kernel(
    const float* __restrict__ x, const float* __restrict__ w,
    ushort_t* __restrict__ y)
{
    const int row = blockIdx.x;
    const float* xr = x + (size_t)row * D_MODEL;
    ushort_t* yr = y + (size_t)row * D_MODEL;
    const int tid = threadIdx.x;

    float v0 = xr[tid], v1 = xr[tid + 256];
    float ss = v0 * v0 + v1 * v1;
    #pragma unroll
    for (int off = 32; off > 0; off >>= 1) ss += __shfl_down(ss, off);

    __shared__ float wsum[4];
    __shared__ float scale_s;
    int wid = tid >> 6, lane = tid & 63;
    if (lane == 0) wsum[wid] = ss;
    __syncthreads();
    if (tid == 0) {
        float tot = wsum[0] + wsum[1] + wsum[2] + wsum[3];
        scale_s = 1.0f / sqrtf(tot / (float)D_MODEL + 1e-5f);
    }
    __syncthreads();
    float sc = scale_s;
    yr[tid] = f2bf(v0 * sc * w[tid]);
    yr[tid + 256] = f2bf(v1 * sc * w[tid + 256]);
}

// ---------------------------------------------------------------------------
// Causal dwconv (K=4) + bias + silu. Reads xp plane of fused xz (stride
// 2048), writes bf16 u only (scan consumes bf16 now).
// ---------------------------------------------------------------------------
__global__ __launch_bounds__(256) void conv_silu_kernel(
    const float* __restrict__ xz, const float* __restrict__ w,
    const float* __restrict__ bconv, ushort_t* __restrict__ outb)
{
    const int idx = blockIdx.x * 256 + threadIdx.x;
    const int d = idx & (D_INNER - 1);
    const int t = (idx >> 10) & (SEQ - 1);
    const int row = idx >> 10;
    const float* base = xz + (size_t)row * 2048 + d;

    float s = 0.f;
    #pragma unroll
    for (int k = 0; k < KCONV; k++) {
        int tt = t + k - (KCONV - 1);
        if (tt >= 0) s = fmaf(base[(ptrdiff_t)(k - (KCONV - 1)) * 2048], w[d * KCONV + k], s);
    }
    s += bconv[d];
    float r = s / (1.f + __expf(-s));
    outb[idx] = f2bf(r);
}

// ---------------------------------------------------------------------------
// Chunked selective scan (3 passes), CLEN=32. dt/B/C in dbl (stride NCAT):
// dbl[row][d]=softplus'ed dt; dbl[row][1024+n]=B[n]; dbl[row][1040+n]=C[n].
// u is bf16 in xb.
// ---------------------------------------------------------------------------
__global__ __launch_bounds__(256) void scan_pass1(
    const float* __restrict__ dbl, const ushort_t* __restrict__ ub,
    const float* __restrict__ A_log,
    float* __restrict__ hfin, float* __restrict__ sumdt)
{
    const int tid = threadIdx.x;
    const int b = blockIdx.x >> 7;
    const int p = (blockIdx.x >> 2) & 31;
    const int d = ((blockIdx.x & 3) << 8) + tid;
    const int t0 = p * CLEN;

    float A[D_STATE];
    #pragma unroll
    for (int n = 0; n < D_STATE; n++) A[n] = -expf(A_log[d * D_STATE + n]);

    float h[D_STATE] = {};
    float sdt = 0.f;

    const float* dtp = dbl + ((size_t)b * SEQ + t0) * NCAT + d;
    const float* bp  = dbl + ((size_t)b * SEQ + t0) * NCAT + 1024;
    const ushort_t* up = ub + ((size_t)b * SEQ + t0) * D_INNER + d;

    for (int t = 0; t < CLEN; t++) {
        float dtv = dtp[(size_t)t * NCAT];
        float uv  = bf2f(up[(size_t)t * D_INNER]);
        float dtu = dtv * uv;
        sdt += dtv;
        #pragma unroll
        for (int n = 0; n < D_STATE; n++)
            h[n] = fmaf(__expf(dtv * A[n]), h[n], dtu * bp[t * NCAT + n]);
    }

    size_t base = (size_t)(b * PCH + p) * D_STATE * D_INNER + d;
    #pragma unroll
    for (int n = 0; n < D_STATE; n++) hfin[base + (size_t)n * D_INNER] = h[n];
    sumdt[(size_t)(b * PCH + p) * D_INNER + d] = sdt;
}

__global__ __launch_bounds__(256) void scan_pass2(
    const float* __restrict__ A_log, const float* __restrict__ sumdt,
    float* __restrict__ hc)
{
    const int tid = threadIdx.x;
    const int b = blockIdx.x >> 6;
    const int n = (blockIdx.x >> 2) & 15;
    const int d = ((blockIdx.x & 3) << 8) + tid;

    const float Aval = -expf(A_log[d * D_STATE + n]);
    float h = 0.f;
    for (int p = 0; p < PCH; p++) {
        size_t idx = ((size_t)(b * PCH + p) * D_STATE + n) * D_INNER + d;
        float fin = hc[idx];
        hc[idx] = h;
        h = fmaf(__expf(Aval * sumdt[(size_t)(b * PCH + p) * D_INNER + d]), h, fin);
    }
}

// pass3: u (bf16, in ub) is read then overwritten IN PLACE with y*silu(z).
// Per-element read-then-write by the same thread; ub deliberately NOT
// __restrict__-paired against itself.
__global__ __launch_bounds__(256) void scan_pass3(
    const float* __restrict__ dbl, const float* __restrict__ xz,
    const float* __restrict__ A_log, const float* __restrict__ Dp,
    const float* __restrict__ hstart, ushort_t* ub)
{
    const int tid = threadIdx.x;
    const int b = blockIdx.x >> 7;
    const int p = (blockIdx.x >> 2) & 31;
    const int d = ((blockIdx.x & 3) << 8) + tid;
    const int t0 = p * CLEN;

    float A[D_STATE];
    #pragma unroll
    for (int n = 0; n < D_STATE; n++) A[n] = -expf(A_log[d * D_STATE + n]);
    const float Dv = Dp[d];

    float h[D_STATE];
    size_t base = (size_t)(b * PCH + p) * D_STATE * D_INNER + d;
    #pragma unroll
    for (int n = 0; n < D_STATE; n++) h[n] = hstart[base + (size_t)n * D_INNER];

    const float* dtp = dbl + ((size_t)b * SEQ + t0) * NCAT + d;
    const float* bp  = dbl + ((size_t)b * SEQ + t0) * NCAT + 1024;
    const float* zp  = xz + ((size_t)b * SEQ + t0) * 2048 + 1024 + d;
    ushort_t* up = ub + ((size_t)b * SEQ + t0) * D_INNER + d;

    for (int t = 0; t < CLEN; t++) {
        float dtv = dtp[(size_t)t * NCAT];
        float uv  = bf2f(up[(size_t)t * D_INNER]);
        float zv  = zp[(size_t)t * 2048];
        float dtu = dtv * uv;
        float y = 0.f;
        #pragma unroll
        for (int n = 0; n < D_STATE; n++) {
            h[n] = fmaf(__expf(dtv * A[n]), h[n], dtu * bp[t * NCAT + n]);
            y = fmaf(h[n], bp[t * NCAT + 16 + n], y);
        }
        float res = fmaf(uv, Dv, y);
        res *= zv / (1.f + __expf(-zv));
        up[(size_t)t * D_INNER] = f2bf(res);
    }
}

// ---------------------------------------------------------------------------
__global__ __launch_bounds__(256) void softmax_kernel(
    const float* __restrict__ in, float* __restrict__ out)
{
    const int idx = blockIdx.x * 256 + threadIdx.x;
    float v = in[idx];
    float m = v;
    #pragma unroll
    for (int off = 16; off > 0; off >>= 1) m = fmaxf(m, __shfl_xor(m, off, 32));
    float e = expf(v - m);
    float s = e;
    #pragma unroll
    for (int off = 16; off > 0; off >>= 1) s += __shfl_xor(s, off, 32);
    out[idx] = e / s;
}

// ---------------------------------------------------------------------------
extern "C" void kernel_launch(void* const* d_in, const int* in_sizes, int n_in,
                              void* d_out, int out_size, void* d_ws, size_t ws_size,
                              hipStream_t stream)
{
    const float* x       = (const float*)d_in[0];
    const float* lin1_w  = (const float*)d_in[1];
    const float* lin1_b  = (const float*)d_in[2];
    const float* norm_w  = (const float*)d_in[3];
    const float* in_w    = (const float*)d_in[4];
    const float* conv_w  = (const float*)d_in[5];
    const float* conv_b  = (const float*)d_in[6];
    const float* xproj_w = (const float*)d_in[7];
    const float* dt_w    = (const float*)d_in[8];
    const float* dt_b    = (const float*)d_in[9];
    const float* A_log   = (const float*)d_in[10];
    const float* Dp      = (const float*)d_in[11];
    const float* out_w   = (const float*)d_in[12];
    const float* lin2_w  = (const float*)d_in[13];
    const float* lin2_b  = (const float*)d_in[14];
    float* outp = (float*)d_out;
    (void)ws_size; (void)in_sizes; (void)n_in; (void)out_size;

    float* ws = (float*)d_ws;
    const size_t F1M = 1u << 20;
    float* h     = ws;                        // 2M fl
    float* xz    = h + 2 * F1M;               // 8M fl (xp | z, stride 2048)
    float* dbl   = xz + 8 * F1M;              // 4.5M fl
    float* sumdt = dbl + (size_t)NTOK * NCAT; // 128K fl
    float* hfin  = sumdt + (size_t)BATCH * PCH * D_INNER; // 2M fl
    ushort_t* hn_bf = (ushort_t*)(hfin + 2 * F1M);        // 2M us
    ushort_t* xb    = hn_bf + 2 * F1M;                    // 4M us
    ushort_t* lin1_wt = xb + 4 * F1M;                     // 512*1024
    ushort_t* in_wt   = lin1_wt + (size_t)512 * 1024;     // 4*2048*512
    ushort_t* out_wt  = in_wt + (size_t)4 * 2048 * 512;   // 4*512*1024
    ushort_t* lin2_wt = out_wt + (size_t)4 * 512 * 1024;  // 1024*512
    ushort_t* wcat    = lin2_wt + (size_t)1024 * 512;     // 4*1152*1024

    dim3 blk(256);

    // --- weight prep ---
    transpose_cast_kernel<<<dim3(512 / 32, 1024 / 32), blk, 0, stream>>>(
        lin1_w, lin1_wt, LATENT, D_MODEL);
    for (int l = 0; l < N_LAYERS; l++) {
        transpose_cast_kernel<<<dim3(2048 / 32, 512 / 32), blk, 0, stream>>>(
            in_w + (size_t)l * 512 * 2048, in_wt + (size_t)l * 2048 * 512, 512, 2048);
        transpose_cast_kernel<<<dim3(512 / 32, 1024 / 32), blk, 0, stream>>>(
            out_w + (size_t)l * 1024 * 512, out_wt + (size_t)l * 512 * 1024, 1024, 512);
    }
    transpose_cast_kernel<<<dim3(1024 / 32, 512 / 32), blk, 0, stream>>>(
        lin2_w, lin2_wt, D_MODEL, LATENT);
    build_wdt_kernel<<<dim3(16, 16, N_LAYERS), blk, 0, stream>>>(
        xproj_w, dt_w, wcat);
    build_wbc_kernel<<<dim3((N_LAYERS * 128 * 1024) / 256), blk, 0, stream>>>(
        xproj_w, wcat);

    // x -> bf16
    cast_bf16_kernel<<<dim3((NTOK * LATENT) / 256), blk, 0, stream>>>(x, xb);

    // lin1: h = x_bf @ lin1_wt^T + b
    gemm_bf16_kernel<<<dim3(D_MODEL / 128, NTOK / 128), blk, 0, stream>>>(
        xb, LATENT, lin1_wt, LATENT, h, D_MODEL, lin1_b,
        NTOK, D_MODEL, LATENT, 1);

    for (int l = 0; l < N_LAYERS; l++) {
        const float* nw = norm_w + (size_t)l * D_MODEL;
        const float* cw = conv_w + (size_t)l * D_INNER * KCONV;
        const float* cb = conv_b + (size_t)l * D_INNER;
        const float* db = dt_b + (size_t)l * D_INNER;
        const float* al = A_log + (size_t)l * D_INNER * D_STATE;
        const float* dp = Dp + (size_t)l * D_INNER;
        const ushort_t* iwt = in_wt + (size_t)l * 2048 * 512;
        const ushort_t* owt = out_wt + (size_t)l * 512 * 1024;
        const ushort_t* wc  = wcat + (size_t)l * NCAT * D_INNER;

        rmsnorm_kernel<<<dim3(NTOK), blk, 0, stream>>>(h, nw, hn_bf);

        // fused in-proj: xz = hn @ in_w[l]  (N=2048, 512 blocks)
        gemm_bf16_kernel<<<dim3(2048 / 128, NTOK / 128), blk, 0, stream>>>(
            hn_bf, D_MODEL, iwt, D_MODEL, xz, 2048, nullptr,
            NTOK, 2048, D_MODEL, 0);

        // conv + silu: xz[:, :1024] -> xb (bf16 u)
        conv_silu_kernel<<<dim3((NTOK * D_INNER) / 256), blk, 0, stream>>>(
            xz, cw, cb, xb);

        // merged xproj+dt GEMM: dbl[:, :1024]=softplus(u@Wdt+dt_b),
        //                       dbl[:, 1024:1056]=B|C
        gemm_bf16_kernel<<<dim3(NCAT / 128, NTOK / 128), blk, 0, stream>>>(
            xb, D_INNER, wc, D_INNER, dbl, NCAT, db,
            NTOK, NCAT, D_INNER, 4);

        // chunked scan; pass3 overwrites xb in place with y*silu(z)
        scan_pass1<<<dim3(BATCH * PCH * (D_INNER / 256)), blk, 0, stream>>>(
            dbl, xb, al, hfin, sumdt);
        scan_pass2<<<dim3(BATCH * D_STATE * (D_INNER / 256)), blk, 0, stream>>>(
            al, sumdt, hfin);
        scan_pass3<<<dim3(BATCH * PCH * (D_INNER / 256)), blk, 0, stream>>>(
            dbl, xz, al, dp, hfin, xb);

        // h += y_bf @ out_wt^T
        gemm_bf16_kernel<<<dim3(D_MODEL / 128, NTOK / 128), blk, 0, stream>>>(
            xb, D_INNER, owt, D_INNER, h, D_MODEL, nullptr,
            NTOK, D_MODEL, D_INNER, 2);
    }

    // h -> bf16, lin2 (logits into xz), softmax
    cast_bf16_kernel<<<dim3((NTOK * D_MODEL) / 256), blk, 0, stream>>>(h, xb);
    gemm_bf16_kernel<<<dim3(LATENT / 128, NTOK / 128), blk, 0, stream>>>(
        xb, D_MODEL, lin2_wt, D_MODEL, xz, LATENT, lin2_b,
        NTOK, LATENT, D_MODEL, 1);
    softmax_kernel<<<dim3((NTOK * LATENT) / 256), blk, 0, stream>>>(xz, outp);
}